// Round 15
// baseline (74.813 us; speedup 1.0000x reference)
//
#include <hip/hip_runtime.h>
#include <hip/hip_bf16.h>

#define BB 2
#define SS 1024
#define DD 1024
#define HH 16
#define HDD 64
#define MASK_VAL -10000.0f
#define LOG2E 1.44269504f
#define BSD (BB * SS * DD)   // 2097152
#define NROW (BB * HH * SS)  // 32768 (bh*1024 + qrow)
#define NKV 2                // split-KV factor

typedef __attribute__((ext_vector_type(8))) short bf16x8;
typedef __attribute__((ext_vector_type(4))) short short4v;
typedef __attribute__((ext_vector_type(4))) float f32x4;
typedef __attribute__((ext_vector_type(16))) float f32x16;
typedef __attribute__((ext_vector_type(4))) unsigned int uint4v;

__device__ __forceinline__ short f2bf(float f) {
    union { float f; unsigned u; } v; v.f = f;
    unsigned r = v.u + 0x7FFFu + ((v.u >> 16) & 1u);   // RN-even
    return (short)(r >> 16);
}
__device__ __forceinline__ float bf2f(short s) {
    union { unsigned u; float f; } v;
    v.u = ((unsigned)(unsigned short)s) << 16;
    return v.f;
}
__device__ __forceinline__ unsigned cvt_pk_bf16(float lo, float hi) {
    unsigned r;
    asm("v_cvt_pk_bf16_f32 %0, %1, %2" : "=v"(r) : "v"(lo), "v"(hi));
    return r;
}
// bare v_exp_f32: computes 2^x (exp2 domain; log2e pre-folded into operands)
__device__ __forceinline__ float v_exp2(float x) {
    float r;
    asm("v_exp_f32 %0, %1" : "=v"(r) : "v"(x));
    return r;
}
__device__ __forceinline__ void plane32_swap(unsigned& a, unsigned& b) {
#if __has_builtin(__builtin_amdgcn_permlane32_swap)
    auto r = __builtin_amdgcn_permlane32_swap(a, b, false, false);
    a = r[0]; b = r[1];
#else
    unsigned as = (unsigned)__shfl_xor((int)a, 32);
    unsigned bs = (unsigned)__shfl_xor((int)b, 32);
    bool lo = ((threadIdx.x & 63) < 32);
    unsigned na = lo ? a : bs;
    unsigned nb = lo ? as : b;
    a = na; b = nb;
#endif
}

// ---------------------------------------------------------------------------
// fused prep, compact grid (3072 blocks): id<1024 -> x_bf = bf16(h0+h1);
// else 4 x 512 blocks -> weight fp32->bf16.
// ---------------------------------------------------------------------------
__global__ __launch_bounds__(256) void k_prep(
    const float* __restrict__ h,
    const float* __restrict__ wq, const float* __restrict__ wk,
    const float* __restrict__ wv, const float* __restrict__ wo,
    short* __restrict__ xbf, short* __restrict__ wbf) {
    int id = blockIdx.x;
    if (id < 1024) {
        int i = id * 256 + threadIdx.x;
        const float4* h0 = (const float4*)h;
        const float4* h1 = (const float4*)(h + (size_t)BSD);
        float4 a0 = h0[2 * i], a1 = h0[2 * i + 1];
        float4 b0 = h1[2 * i], b1 = h1[2 * i + 1];
        bf16x8 o;
        o[0] = f2bf(a0.x + b0.x); o[1] = f2bf(a0.y + b0.y);
        o[2] = f2bf(a0.z + b0.z); o[3] = f2bf(a0.w + b0.w);
        o[4] = f2bf(a1.x + b1.x); o[5] = f2bf(a1.y + b1.y);
        o[6] = f2bf(a1.z + b1.z); o[7] = f2bf(a1.w + b1.w);
        ((bf16x8*)xbf)[i] = o;
    } else {
        int zi = (id - 1024) >> 9;                     // 0..3
        int i = ((id - 1024) & 511) * 256 + threadIdx.x;
        const float* src = (zi == 0) ? wq : (zi == 1) ? wk : (zi == 2) ? wv : wo;
        short* dst = wbf + (size_t)zi * (DD * DD);
        const float4* s4 = (const float4*)src;
        float4 a0 = s4[2 * i], a1 = s4[2 * i + 1];
        bf16x8 o;
        o[0] = f2bf(a0.x); o[1] = f2bf(a0.y); o[2] = f2bf(a0.z); o[3] = f2bf(a0.w);
        o[4] = f2bf(a1.x); o[5] = f2bf(a1.y); o[6] = f2bf(a1.z); o[7] = f2bf(a1.w);
        ((bf16x8*)dst)[i] = o;
    }
}

// ---------------------------------------------------------------------------
// QKV bf16 MFMA GEMM, 128x64 tile, BK=64, 256 threads (4 waves, 2Mx2N).
// XOR chunk-swizzled LDS (T2, R14-verified) + NEW 2-phase pipeline (T3 min
// recipe): stage(k+1) issued BEFORE compute(k); ONE __syncthreads per tile
// (its vmcnt(0) drain now waits on loads that had a full compute to land).
// Double-buffered LDS 48 KB -> still 3 blocks/CU.
// z=0,1 -> bf16 out [B,S,D] + bias; z=2 -> V^T out [B*H][64][S] + bias.
// ---------------------------------------------------------------------------
#define QBM 128
#define QBN 64
#define QBK 64

__global__ __launch_bounds__(256) void k_gemm_qkv(
    const short* __restrict__ xbf, const short* __restrict__ wbf,
    const float* __restrict__ bq, const float* __restrict__ bk,
    const float* __restrict__ bv,
    short* __restrict__ qb, short* __restrict__ kb, short* __restrict__ vt) {
    __shared__ __align__(16) short As[2][QBM * QBK];   // 32 KB
    __shared__ __align__(16) short Bs[2][QBN * QBK];   // 16 KB
    const int z = blockIdx.z;
    const short* W = wbf + (size_t)z * (DD * DD);
    const float* bias = (z == 0) ? bq : (z == 1) ? bk : bv;
    const int bm = blockIdx.y * QBM;
    const int bn = blockIdx.x * QBN;
    const int tid = threadIdx.x;
    const int lane = tid & 63;
    const int wid = tid >> 6;
    const int wm = wid >> 1;
    const int wn = wid & 1;
    const int lr = lane & 15;
    const int kq = lane >> 4;

    f32x4 acc[4][2];
#pragma unroll
    for (int i = 0; i < 4; ++i)
#pragma unroll
        for (int j = 0; j < 2; ++j) acc[i][j] = (f32x4)0.0f;

    auto stage = [&](int k0, int bi) {
#pragma unroll
        for (int i = 0; i < 4; ++i) {           // A: 128 rows x 64 k
            int s = i * 256 + tid;              // 0..1023
            int r = s >> 3;                     // 0..127
            int cs = (s & 7) ^ (r & 7);         // inverse-swizzled source chunk
            __builtin_amdgcn_global_load_lds(
                (const __attribute__((address_space(1))) unsigned*)(xbf + (size_t)(bm + r) * DD + k0 + (cs << 3)),
                (__attribute__((address_space(3))) unsigned*)&As[bi][s * 8], 16, 0, 0);
        }
#pragma unroll
        for (int i = 0; i < 2; ++i) {           // B: 64 rows x 64 k
            int s = i * 256 + tid;              // 0..511
            int r = s >> 3;                     // 0..63
            int cs = (s & 7) ^ (r & 7);
            __builtin_amdgcn_global_load_lds(
                (const __attribute__((address_space(1))) unsigned*)(W + (size_t)(bn + r) * DD + k0 + (cs << 3)),
                (__attribute__((address_space(3))) unsigned*)&Bs[bi][s * 8], 16, 0, 0);
        }
    };

    stage(0, 0);
    __syncthreads();                            // prologue: full latency once
#pragma unroll 1
    for (int kt = 0; kt < 16; ++kt) {
        if (kt < 15) stage((kt + 1) * QBK, (kt + 1) & 1);   // prefetch next
        const short* Ab = &As[kt & 1][0];
        const short* Bb = &Bs[kt & 1][0];

        bf16x8 af[4][2], bfr[2][2];
#pragma unroll
        for (int f = 0; f < 4; ++f) {
            int row = wm * 64 + f * 16 + lr;
#pragma unroll
            for (int ks = 0; ks < 2; ++ks) {
                int cpos = ((ks << 2) | kq) ^ (row & 7);
                af[f][ks] = *(const bf16x8*)&Ab[row * QBK + (cpos << 3)];
            }
        }
#pragma unroll
        for (int g = 0; g < 2; ++g) {
            int row = wn * 32 + g * 16 + lr;
#pragma unroll
            for (int ks = 0; ks < 2; ++ks) {
                int cpos = ((ks << 2) | kq) ^ (row & 7);
                bfr[g][ks] = *(const bf16x8*)&Bb[row * QBK + (cpos << 3)];
            }
        }
#pragma unroll
        for (int fm = 0; fm < 4; ++fm)
#pragma unroll
            for (int fn = 0; fn < 2; ++fn)
#pragma unroll
                for (int ks = 0; ks < 2; ++ks)
                    acc[fm][fn] = __builtin_amdgcn_mfma_f32_16x16x32_bf16(
                        af[fm][ks], bfr[fn][ks], acc[fm][fn], 0, 0, 0);
        __syncthreads();   // one sync/tile: drains stage(kt+1) (overlapped) + read-guard
    }

    if (z < 2) {
        short* C = (z == 0) ? qb : kb;
#pragma unroll
        for (int fm = 0; fm < 4; ++fm) {
            int row0 = bm + wm * 64 + fm * 16 + kq * 4;
#pragma unroll
            for (int fn = 0; fn < 2; ++fn) {
                int col = bn + wn * 32 + fn * 16 + lr;
                float bv_ = bias[col];
#pragma unroll
                for (int j = 0; j < 4; ++j)
                    C[(size_t)(row0 + j) * DD + col] = f2bf(acc[fm][fn][j] + bv_);
            }
        }
    } else {
#pragma unroll
        for (int fm = 0; fm < 4; ++fm) {
            int row0 = bm + wm * 64 + fm * 16 + kq * 4;
            int bidx = row0 >> 10, s0 = row0 & 1023;
#pragma unroll
            for (int fn = 0; fn < 2; ++fn) {
                int col = bn + wn * 32 + fn * 16 + lr;
                float bv_ = bias[col];
                size_t addr = ((size_t)(bidx * HH + (col >> 6)) * HDD + (col & 63)) * SS + s0;
                short4v o;
                o.x = f2bf(acc[fm][fn][0] + bv_); o.y = f2bf(acc[fm][fn][1] + bv_);
                o.z = f2bf(acc[fm][fn][2] + bv_); o.w = f2bf(acc[fm][fn][3] + bv_);
                *(short4v*)&vt[addr] = o;
            }
        }
    }
}

// ---------------------------------------------------------------------------
// Output GEMM with fused NKV-way split-KV merge. 64x64 tile, BK=64, 256 thr.
// XOR chunk-swizzle (R14-verified) + 2-phase pipeline: B-stage(k+1) gloads
// and A-merge(k+1) (Op reg-loads -> ds_write) issued BEFORE compute(k);
// one __syncthreads per tile. m/l in exp2 domain.
// ---------------------------------------------------------------------------
#define OM 64
#define ON 64
#define OK 64

__global__ __launch_bounds__(256) void k_gemm_out_fused(
    const short* __restrict__ Op, const float* __restrict__ Mp,
    const float* __restrict__ Lp, const short* __restrict__ W,
    const float* __restrict__ bias, float* __restrict__ C) {
    __shared__ __align__(16) short As[2][OM * OK];   // 16 KB
    __shared__ __align__(16) short Bs[2][ON * OK];   // 16 KB
    const int bm = blockIdx.y * OM;
    const int bn = blockIdx.x * ON;
    const int tid = threadIdx.x;
    const int lane = tid & 63;
    const int wid = tid >> 6;
    const int wm = wid & 1;
    const int wn = wid >> 1;
    const int lr = lane & 15;
    const int kq = lane >> 4;

    f32x4 acc[2][2];
#pragma unroll
    for (int i = 0; i < 2; ++i)
#pragma unroll
        for (int j = 0; j < 2; ++j) acc[i][j] = (f32x4)0.0f;

    auto stageB = [&](int k0, int bi) {
#pragma unroll
        for (int i = 0; i < 2; ++i) {
            int t2 = i * 256 + tid;
            int br = t2 >> 3;
            int cs = (t2 & 7) ^ (br & 7);       // inverse-swizzled source chunk
            __builtin_amdgcn_global_load_lds(
                (const __attribute__((address_space(1))) unsigned*)(W + (size_t)(bn + br) * DD + k0 + (cs << 3)),
                (__attribute__((address_space(3))) unsigned*)&Bs[bi][t2 * 8], 16, 0, 0);
        }
    };
    auto mergeA = [&](int k0, int bi) {
        int hh = k0 >> 6;
#pragma unroll
        for (int i = 0; i < 2; ++i) {
            int t2 = i * 256 + tid;
            int ar = t2 >> 3;
            int p = t2 & 7;
            int d0 = (p ^ (ar & 7)) << 3;       // write pos p holds d-chunk p^(ar&7)
            int grow = bm + ar;
            int b = grow >> 10;
            int s = grow & 1023;
            int hrow = ((b * HH + hh) << 10) + s;
            float m1 = Mp[hrow], m2 = Mp[NROW + hrow];
            float l1 = Lp[hrow], l2 = Lp[NROW + hrow];
            float m = fmaxf(m1, m2);
            float a1 = v_exp2(m1 - m), a2 = v_exp2(m2 - m);
            float inv = 1.0f / (l1 * a1 + l2 * a2);
            float c1 = a1 * inv, c2 = a2 * inv;
            bf16x8 o1 = *(const bf16x8*)&Op[(size_t)hrow * HDD + d0];
            bf16x8 o2 = *(const bf16x8*)&Op[((size_t)NROW + hrow) * HDD + d0];
            bf16x8 av;
#pragma unroll
            for (int e = 0; e < 8; ++e)
                av[e] = f2bf(bf2f(o1[e]) * c1 + bf2f(o2[e]) * c2);
            *(bf16x8*)&As[bi][t2 * 8] = av;
        }
    };

    stageB(0, 0);
    mergeA(0, 0);
    __syncthreads();
#pragma unroll 1
    for (int kt = 0; kt < 16; ++kt) {
        if (kt < 15) { stageB((kt + 1) * OK, (kt + 1) & 1); mergeA((kt + 1) * OK, (kt + 1) & 1); }
        const short* Ab = &As[kt & 1][0];
        const short* Bb = &Bs[kt & 1][0];

        bf16x8 af[2][2], bfr[2][2];
#pragma unroll
        for (int f = 0; f < 2; ++f) {
            int rowa = wm * 32 + f * 16 + lr;
            int rowb = wn * 32 + f * 16 + lr;
#pragma unroll
            for (int ks = 0; ks < 2; ++ks) {
                int ca = (((ks << 2) | kq)) ^ (rowa & 7);
                int cb = (((ks << 2) | kq)) ^ (rowb & 7);
                af[f][ks] = *(const bf16x8*)&Ab[rowa * OK + (ca << 3)];
                bfr[f][ks] = *(const bf16x8*)&Bb[rowb * OK + (cb << 3)];
            }
        }
#pragma unroll
        for (int fm = 0; fm < 2; ++fm)
#pragma unroll
            for (int fn = 0; fn < 2; ++fn)
#pragma unroll
                for (int ks = 0; ks < 2; ++ks)
                    acc[fm][fn] = __builtin_amdgcn_mfma_f32_16x16x32_bf16(
                        af[fm][ks], bfr[fn][ks], acc[fm][fn], 0, 0, 0);
        __syncthreads();
    }

#pragma unroll
    for (int fm = 0; fm < 2; ++fm) {
        int row0 = bm + wm * 32 + fm * 16 + kq * 4;
#pragma unroll
        for (int fn = 0; fn < 2; ++fn) {
            int col = bn + wn * 32 + fn * 16 + lr;
            float bv_ = bias[col];
#pragma unroll
            for (int j = 0; j < 4; ++j)
                C[(size_t)(row0 + j) * DD + col] = acc[fm][fn][j] + bv_;
        }
    }
}

// ---------------------------------------------------------------------------
// MFMA flash attention — R11-EXACT (best measured): swapped-QK^T 32x32,
// split-KV x2, exp2 softmax, dbuf LDS, split K/V waits.
// ---------------------------------------------------------------------------
__global__ __launch_bounds__(256) void k_attn(
    const short* __restrict__ qb, const short* __restrict__ kb,
    const short* __restrict__ vt, const float* __restrict__ mask,
    short* __restrict__ Op, float* __restrict__ Mp, float* __restrict__ Lp) {
    __shared__ __align__(16) short Kls[2][64 * 64];
    __shared__ __align__(16) short Vls[2][64 * 64];

    const int bh = blockIdx.y;
    const int b = bh >> 4;
    const int h = bh & 15;
    const int q0 = blockIdx.x << 7;
    const int kvh = blockIdx.z;
    const int tbase = kvh << 9;          // 0 or 512
    const int tid = threadIdx.x;
    const int lane = tid & 63;
    const int w = tid >> 6;
    const int ql = lane & 31;
    const int hi = lane >> 5;
    const int rsw = ql & 7;
    const float scale2 = 0.125f * LOG2E;
    const float mval2 = MASK_VAL * LOG2E;

    const short* khead = kb + (size_t)b * SS * DD + h * HDD;
    const short* vhead = vt + (size_t)bh * HDD * SS;
    const float* maskp = mask + b * SS;

    bf16x8 qf0, qf1, qf2, qf3;
    {
        const short* qrow = qb + ((size_t)(b * SS + q0 + w * 32 + ql)) * DD + h * HDD + hi * 8;
        qf0 = *(const bf16x8*)(qrow);
        qf1 = *(const bf16x8*)(qrow + 16);
        qf2 = *(const bf16x8*)(qrow + 32);
        qf3 = *(const bf16x8*)(qrow + 48);
    }

    auto stage = [&](int t0, int bi) {
        const short* kbase = khead + (size_t)t0 * DD;
        const short* vbase = vhead + t0;
#pragma unroll
        for (int i = 0; i < 2; ++i) {
            int t = i * 256 + tid;
            int r = t >> 3;
            int cs = (t & 7) ^ (r & 7);
            __builtin_amdgcn_global_load_lds(
                (const __attribute__((address_space(1))) unsigned*)(kbase + (size_t)r * DD + cs * 8),
                (__attribute__((address_space(3))) unsigned*)&Kls[bi][t * 8], 16, 0, 0);
        }
#pragma unroll
        for (int i = 0; i < 2; ++i) {
            int t = i * 256 + tid;
            int r = t >> 3;
            int cs = (t & 7) ^ (r & 7);
            __builtin_amdgcn_global_load_lds(
                (const __attribute__((address_space(1))) unsigned*)(vbase + (size_t)r * SS + cs * 8),
                (__attribute__((address_space(3))) unsigned*)&Vls[bi][t * 8], 16, 0, 0);
        }
    };

    float m_r = -3.0e38f, l_r = 0.0f;
    f32x16 O0 = (f32x16)0.0f, O1 = (f32x16)0.0f;

    auto body = [&](int t0, int cur, int tail) {
        const short* Kb = &Kls[cur][0];
        const short* Vb = &Vls[cur][0];

        f32x16 s0 = (f32x16)0.0f, s1 = (f32x16)0.0f;
        __builtin_amdgcn_s_setprio(1);
#pragma unroll
        for (int step = 0; step < 4; ++step) {
            int cpos = ((step << 1) | hi) ^ rsw;
            bf16x8 k0 = *(const bf16x8*)&Kb[ql * 64 + (cpos << 3)];
            bf16x8 k1 = *(const bf16x8*)&Kb[(32 + ql) * 64 + (cpos << 3)];
            bf16x8 qf = (step == 0) ? qf0 : (step == 1) ? qf1 : (step == 2) ? qf2 : qf3;
            s0 = __builtin_amdgcn_mfma_f32_32x32x16_bf16(k0, qf, s0, 0, 0, 0);
            s1 = __builtin_amdgcn_mfma_f32_32x32x16_bf16(k1, qf, s1, 0, 0, 0);
        }
        __builtin_amdgcn_s_setprio(0);

#pragma unroll
        for (int g = 0; g < 4; ++g) {
            float4 a4 = *(const float4*)&maskp[t0 + 8 * g + 4 * hi];
            float4 b4 = *(const float4*)&maskp[t0 + 32 + 8 * g + 4 * hi];
            s0[4 * g + 0] = fmaf(s0[4 * g + 0], scale2, (1.0f - a4.x) * mval2);
            s0[4 * g + 1] = fmaf(s0[4 * g + 1], scale2, (1.0f - a4.y) * mval2);
            s0[4 * g + 2] = fmaf(s0[4 * g + 2], scale2, (1.0f - a4.z) * mval2);
            s0[4 * g + 3] = fmaf(s0[4 * g + 3], scale2, (1.0f - a4.w) * mval2);
            s1[4 * g + 0] = fmaf(s1[4 * g + 0], scale2, (1.0f - b4.x) * mval2);
            s1[4 * g + 1] = fmaf(s1[4 * g + 1], scale2, (1.0f - b4.y) * mval2);
            s1[4 * g + 2] = fmaf(s1[4 * g + 2], scale2, (1.0f - b4.z) * mval2);
            s1[4 * g + 3] = fmaf(s1[4 * g + 3], scale2, (1.0f - b4.w) * mval2);
        }

        float mt[16];
#pragma unroll
        for (int r = 0; r < 16; ++r) mt[r] = fmaxf(s0[r], s1[r]);
#pragma unroll
        for (int st = 8; st > 0; st >>= 1)
#pragma unroll
            for (int r = 0; r < 8; ++r)
                if (r < st) mt[r] = fmaxf(mt[r], mt[r + st]);
        float mx = fmaxf(mt[0], __shfl_xor(mt[0], 32));

        bool need = mx > m_r + 8.0f;   // exp2 domain: P bounded by 2^8
        if (__any(need)) {
            float mn = fmaxf(m_r, mx);
            float alpha = v_exp2(m_r - mn);
            m_r = mn;
            l_r *= alpha;
#pragma unroll
            for (int r = 0; r < 16; ++r) {
                int qrow = (r & 3) + 8 * (r >> 2) + 4 * hi;
                float al = __shfl(alpha, qrow, 64);
                O0[r] *= al;
                O1[r] *= al;
            }
        }

        float st0[16];
#pragma unroll
        for (int r = 0; r < 16; ++r) {
            s0[r] = v_exp2(s0[r] - m_r);
            s1[r] = v_exp2(s1[r] - m_r);
            st0[r] = s0[r] + s1[r];
        }
#pragma unroll
        for (int st = 8; st > 0; st >>= 1)
#pragma unroll
            for (int r = 0; r < 8; ++r)
                if (r < st) st0[r] += st0[r + st];
        l_r += st0[0] + __shfl_xor(st0[0], 32);

        unsigned w0 = cvt_pk_bf16(s0[0], s0[1]),  w1 = cvt_pk_bf16(s0[2], s0[3]);
        unsigned w2 = cvt_pk_bf16(s0[4], s0[5]),  w3 = cvt_pk_bf16(s0[6], s0[7]);
        unsigned w4 = cvt_pk_bf16(s0[8], s0[9]),  w5 = cvt_pk_bf16(s0[10], s0[11]);
        unsigned w6 = cvt_pk_bf16(s0[12], s0[13]), w7 = cvt_pk_bf16(s0[14], s0[15]);
        plane32_swap(w0, w2); plane32_swap(w1, w3);
        plane32_swap(w4, w6); plane32_swap(w5, w7);
        uint4v f0 = {w0, w1, w2, w3};
        uint4v f1 = {w4, w5, w6, w7};
        unsigned x0 = cvt_pk_bf16(s1[0], s1[1]),  x1 = cvt_pk_bf16(s1[2], s1[3]);
        unsigned x2 = cvt_pk_bf16(s1[4], s1[5]),  x3 = cvt_pk_bf16(s1[6], s1[7]);
        unsigned x4 = cvt_pk_bf16(s1[8], s1[9]),  x5 = cvt_pk_bf16(s1[10], s1[11]);
        unsigned x6 = cvt_pk_bf16(s1[12], s1[13]), x7 = cvt_pk_bf16(s1[14], s1[15]);
        plane32_swap(x0, x2); plane32_swap(x1, x3);
        plane32_swap(x4, x6); plane32_swap(x5, x7);
        uint4v f2 = {x0, x1, x2, x3};
        uint4v f3 = {x4, x5, x6, x7};

        bf16x8 pf0 = __builtin_bit_cast(bf16x8, f0);
        bf16x8 pf1 = __builtin_bit_cast(bf16x8, f1);
        bf16x8 pf2 = __builtin_bit_cast(bf16x8, f2);
        bf16x8 pf3 = __builtin_bit_cast(bf16x8, f3);

        if (tail) { asm volatile("s_waitcnt vmcnt(0)\n\ts_barrier" ::: "memory"); }
        else      { asm volatile("s_waitcnt vmcnt(4)\n\ts_barrier" ::: "memory"); }

        __builtin_amdgcn_s_setprio(1);
#pragma unroll
        for (int ks = 0; ks < 4; ++ks) {
            int cpos = ((ks << 1) | hi) ^ rsw;
            bf16x8 pf = (ks == 0) ? pf0 : (ks == 1) ? pf1 : (ks == 2) ? pf2 : pf3;
            bf16x8 v0 = *(const bf16x8*)&Vb[ql * 64 + (cpos << 3)];
            bf16x8 v1 = *(const bf16x8*)&Vb[(32 + ql) * 64 + (cpos << 3)];
            O0 = __builtin_amdgcn_mfma_f32_32x32x16_bf16(pf, v0, O0, 0, 0, 0);
            O1 = __builtin_amdgcn_mfma_f32_32x32x16_bf16(pf, v1, O1, 0, 0, 0);
        }
        __builtin_amdgcn_s_setprio(0);
    };

    stage(tbase, 0);
    for (int it = 0; it < 7; ++it) {
        stage(tbase + ((it + 1) << 6), (it + 1) & 1);
        asm volatile("s_waitcnt vmcnt(6)\n\ts_barrier" ::: "memory");   // K(it) ready
        body(tbase + (it << 6), it & 1, 0);
        asm volatile("s_barrier" ::: "memory");                         // buf reuse guard
    }
    asm volatile("s_waitcnt vmcnt(2)\n\ts_barrier" ::: "memory");       // K(7) ready
    body(tbase + (7 << 6), 1, 1);

    const int rowb = bh * SS + q0 + w * 32;
    short* ob = Op + ((size_t)kvh * NROW + rowb) * HDD;
#pragma unroll
    for (int r = 0; r < 16; ++r) {
        int qrow = (r & 3) + 8 * (r >> 2) + 4 * hi;
        ob[(size_t)qrow * HDD + ql] = f2bf(O0[r]);
        ob[(size_t)qrow * HDD + 32 + ql] = f2bf(O1[r]);
    }
    if (lane < 32) {
        Mp[kvh * NROW + rowb + lane] = m_r;
        Lp[kvh * NROW + rowb + lane] = l_r;
    }
}

// ---------------------------------------------------------------------------
extern "C" void kernel_launch(void* const* d_in, const int* in_sizes, int n_in,
                              void* d_out, int out_size, void* d_ws, size_t ws_size,
                              hipStream_t stream) {
    const float* h    = (const float*)d_in[0];
    const float* mask = (const float*)d_in[1];
    const float* wq   = (const float*)d_in[2];
    const float* bq   = (const float*)d_in[3];
    const float* wk   = (const float*)d_in[4];
    const float* bk   = (const float*)d_in[5];
    const float* wv   = (const float*)d_in[6];
    const float* bv   = (const float*)d_in[7];
    const float* wo   = (const float*)d_in[8];
    const float* bo   = (const float*)d_in[9];
    float* out = (float*)d_out;

    char* base = (char*)d_ws;
    short* x_bf  = (short*)base;                       // 4 MB @ 0
    short* w_bf  = (short*)(base + (4u << 20));        // 8 MB @ 4
    short* q_bf  = (short*)(base + (12u << 20));       // 4 MB @ 12
    short* k_bf  = (short*)(base + (16u << 20));       // 4 MB @ 16
    short* v_t   = (short*)(base + (20u << 20));       // 4 MB @ 20
    short* Op    = (short*)(base + (24u << 20));       // 8 MB @ 24
    float* Mp    = (float*)(base + (40u << 20));       // 256 KB
    float* Lp    = (float*)(base + (40u << 20) + (NKV * NROW * sizeof(float)));

    k_prep<<<3072, 256, 0, stream>>>(h, wq, wk, wv, wo, x_bf, w_bf);

    dim3 gqkv(DD / QBN, BB * SS / QBM, 3);
    k_gemm_qkv<<<gqkv, 256, 0, stream>>>(x_bf, w_bf, bq, bk, bv, q_bf, k_bf, v_t);

    dim3 gattn(SS / 128, BB * HH, NKV);
    k_attn<<<gattn, 256, 0, stream>>>(q_bf, k_bf, v_t, mask, Op, Mp, Lp);

    dim3 gout(DD / ON, BB * SS / OM);
    k_gemm_out_fused<<<gout, 256, 0, stream>>>(Op, Mp, Lp, w_bf + (size_t)3 * DD * DD, bo, out);
}

// Round 16
// 73.652 us; speedup vs baseline: 1.0158x; 1.0158x over previous
//
#include <hip/hip_runtime.h>
#include <hip/hip_bf16.h>

#define BB 2
#define SS 1024
#define DD 1024
#define HH 16
#define HDD 64
#define MASK_VAL -10000.0f
#define LOG2E 1.44269504f
#define BSD (BB * SS * DD)   // 2097152
#define NROW (BB * HH * SS)  // 32768 (bh*1024 + qrow)
#define NKV 2                // split-KV factor

typedef __attribute__((ext_vector_type(8))) short bf16x8;
typedef __attribute__((ext_vector_type(4))) short short4v;
typedef __attribute__((ext_vector_type(4))) float f32x4;
typedef __attribute__((ext_vector_type(16))) float f32x16;
typedef __attribute__((ext_vector_type(4))) unsigned int uint4v;

__device__ __forceinline__ short f2bf(float f) {
    union { float f; unsigned u; } v; v.f = f;
    unsigned r = v.u + 0x7FFFu + ((v.u >> 16) & 1u);   // RN-even
    return (short)(r >> 16);
}
__device__ __forceinline__ float bf2f(short s) {
    union { unsigned u; float f; } v;
    v.u = ((unsigned)(unsigned short)s) << 16;
    return v.f;
}
__device__ __forceinline__ unsigned cvt_pk_bf16(float lo, float hi) {
    unsigned r;
    asm("v_cvt_pk_bf16_f32 %0, %1, %2" : "=v"(r) : "v"(lo), "v"(hi));
    return r;
}
// bare v_exp_f32: computes 2^x (exp2 domain; log2e pre-folded into operands)
__device__ __forceinline__ float v_exp2(float x) {
    float r;
    asm("v_exp_f32 %0, %1" : "=v"(r) : "v"(x));
    return r;
}
__device__ __forceinline__ void plane32_swap(unsigned& a, unsigned& b) {
#if __has_builtin(__builtin_amdgcn_permlane32_swap)
    auto r = __builtin_amdgcn_permlane32_swap(a, b, false, false);
    a = r[0]; b = r[1];
#else
    unsigned as = (unsigned)__shfl_xor((int)a, 32);
    unsigned bs = (unsigned)__shfl_xor((int)b, 32);
    bool lo = ((threadIdx.x & 63) < 32);
    unsigned na = lo ? a : bs;
    unsigned nb = lo ? as : b;
    a = na; b = nb;
#endif
}

// ---------------------------------------------------------------------------
// fused prep, compact grid (3072 blocks)
// ---------------------------------------------------------------------------
__global__ __launch_bounds__(256) void k_prep(
    const float* __restrict__ h,
    const float* __restrict__ wq, const float* __restrict__ wk,
    const float* __restrict__ wv, const float* __restrict__ wo,
    short* __restrict__ xbf, short* __restrict__ wbf) {
    int id = blockIdx.x;
    if (id < 1024) {
        int i = id * 256 + threadIdx.x;
        const float4* h0 = (const float4*)h;
        const float4* h1 = (const float4*)(h + (size_t)BSD);
        float4 a0 = h0[2 * i], a1 = h0[2 * i + 1];
        float4 b0 = h1[2 * i], b1 = h1[2 * i + 1];
        bf16x8 o;
        o[0] = f2bf(a0.x + b0.x); o[1] = f2bf(a0.y + b0.y);
        o[2] = f2bf(a0.z + b0.z); o[3] = f2bf(a0.w + b0.w);
        o[4] = f2bf(a1.x + b1.x); o[5] = f2bf(a1.y + b1.y);
        o[6] = f2bf(a1.z + b1.z); o[7] = f2bf(a1.w + b1.w);
        ((bf16x8*)xbf)[i] = o;
    } else {
        int zi = (id - 1024) >> 9;
        int i = ((id - 1024) & 511) * 256 + threadIdx.x;
        const float* src = (zi == 0) ? wq : (zi == 1) ? wk : (zi == 2) ? wv : wo;
        short* dst = wbf + (size_t)zi * (DD * DD);
        const float4* s4 = (const float4*)src;
        float4 a0 = s4[2 * i], a1 = s4[2 * i + 1];
        bf16x8 o;
        o[0] = f2bf(a0.x); o[1] = f2bf(a0.y); o[2] = f2bf(a0.z); o[3] = f2bf(a0.w);
        o[4] = f2bf(a1.x); o[5] = f2bf(a1.y); o[6] = f2bf(a1.z); o[7] = f2bf(a1.w);
        ((bf16x8*)dst)[i] = o;
    }
}

// ---------------------------------------------------------------------------
// QKV bf16 MFMA GEMM — R14-exact (best measured): 128x64 tile, BK=64,
// XOR chunk-swizzled LDS, single-buffer 2-barrier loop.
// ---------------------------------------------------------------------------
#define QBM 128
#define QBN 64
#define QBK 64

__global__ __launch_bounds__(256) void k_gemm_qkv(
    const short* __restrict__ xbf, const short* __restrict__ wbf,
    const float* __restrict__ bq, const float* __restrict__ bk,
    const float* __restrict__ bv,
    short* __restrict__ qb, short* __restrict__ kb, short* __restrict__ vt) {
    __shared__ __align__(16) short As[QBM * QBK];   // 16 KB
    __shared__ __align__(16) short Bs[QBN * QBK];   // 8 KB
    const int z = blockIdx.z;
    const short* W = wbf + (size_t)z * (DD * DD);
    const float* bias = (z == 0) ? bq : (z == 1) ? bk : bv;
    const int bm = blockIdx.y * QBM;
    const int bn = blockIdx.x * QBN;
    const int tid = threadIdx.x;
    const int lane = tid & 63;
    const int wid = tid >> 6;
    const int wm = wid >> 1;
    const int wn = wid & 1;
    const int lr = lane & 15;
    const int kq = lane >> 4;

    f32x4 acc[4][2];
#pragma unroll
    for (int i = 0; i < 4; ++i)
#pragma unroll
        for (int j = 0; j < 2; ++j) acc[i][j] = (f32x4)0.0f;

    for (int k0 = 0; k0 < DD; k0 += QBK) {
#pragma unroll
        for (int i = 0; i < 4; ++i) {           // A: 128 rows x 64 k
            int s = i * 256 + tid;
            int r = s >> 3;
            int cs = (s & 7) ^ (r & 7);
            __builtin_amdgcn_global_load_lds(
                (const __attribute__((address_space(1))) unsigned*)(xbf + (size_t)(bm + r) * DD + k0 + (cs << 3)),
                (__attribute__((address_space(3))) unsigned*)&As[s * 8], 16, 0, 0);
        }
#pragma unroll
        for (int i = 0; i < 2; ++i) {           // B: 64 rows x 64 k
            int s = i * 256 + tid;
            int r = s >> 3;
            int cs = (s & 7) ^ (r & 7);
            __builtin_amdgcn_global_load_lds(
                (const __attribute__((address_space(1))) unsigned*)(W + (size_t)(bn + r) * DD + k0 + (cs << 3)),
                (__attribute__((address_space(3))) unsigned*)&Bs[s * 8], 16, 0, 0);
        }
        __syncthreads();

        bf16x8 af[4][2], bfr[2][2];
#pragma unroll
        for (int f = 0; f < 4; ++f) {
            int row = wm * 64 + f * 16 + lr;
#pragma unroll
            for (int ks = 0; ks < 2; ++ks) {
                int cpos = ((ks << 2) | kq) ^ (row & 7);
                af[f][ks] = *(const bf16x8*)&As[row * QBK + (cpos << 3)];
            }
        }
#pragma unroll
        for (int g = 0; g < 2; ++g) {
            int row = wn * 32 + g * 16 + lr;
#pragma unroll
            for (int ks = 0; ks < 2; ++ks) {
                int cpos = ((ks << 2) | kq) ^ (row & 7);
                bfr[g][ks] = *(const bf16x8*)&Bs[row * QBK + (cpos << 3)];
            }
        }
#pragma unroll
        for (int fm = 0; fm < 4; ++fm)
#pragma unroll
            for (int fn = 0; fn < 2; ++fn)
#pragma unroll
                for (int ks = 0; ks < 2; ++ks)
                    acc[fm][fn] = __builtin_amdgcn_mfma_f32_16x16x32_bf16(
                        af[fm][ks], bfr[fn][ks], acc[fm][fn], 0, 0, 0);
        __syncthreads();
    }

    if (z < 2) {
        short* C = (z == 0) ? qb : kb;
#pragma unroll
        for (int fm = 0; fm < 4; ++fm) {
            int row0 = bm + wm * 64 + fm * 16 + kq * 4;
#pragma unroll
            for (int fn = 0; fn < 2; ++fn) {
                int col = bn + wn * 32 + fn * 16 + lr;
                float bv_ = bias[col];
#pragma unroll
                for (int j = 0; j < 4; ++j)
                    C[(size_t)(row0 + j) * DD + col] = f2bf(acc[fm][fn][j] + bv_);
            }
        }
    } else {
#pragma unroll
        for (int fm = 0; fm < 4; ++fm) {
            int row0 = bm + wm * 64 + fm * 16 + kq * 4;
            int bidx = row0 >> 10, s0 = row0 & 1023;
#pragma unroll
            for (int fn = 0; fn < 2; ++fn) {
                int col = bn + wn * 32 + fn * 16 + lr;
                float bv_ = bias[col];
                size_t addr = ((size_t)(bidx * HH + (col >> 6)) * HDD + (col & 63)) * SS + s0;
                short4v o;
                o.x = f2bf(acc[fm][fn][0] + bv_); o.y = f2bf(acc[fm][fn][1] + bv_);
                o.z = f2bf(acc[fm][fn][2] + bv_); o.w = f2bf(acc[fm][fn][3] + bv_);
                *(short4v*)&vt[addr] = o;
            }
        }
    }
}

// ---------------------------------------------------------------------------
// Output GEMM with fused split-KV merge — R14-exact. 64x64 tile, BK=64,
// XOR chunk-swizzle both tiles, single-buffer loop. m/l in exp2 domain.
// ---------------------------------------------------------------------------
#define OM 64
#define ON 64
#define OK 64

__global__ __launch_bounds__(256) void k_gemm_out_fused(
    const short* __restrict__ Op, const float* __restrict__ Mp,
    const float* __restrict__ Lp, const short* __restrict__ W,
    const float* __restrict__ bias, float* __restrict__ C) {
    __shared__ __align__(16) short As[OM * OK];   // 8 KB
    __shared__ __align__(16) short Bs[ON * OK];   // 8 KB
    const int bm = blockIdx.y * OM;
    const int bn = blockIdx.x * ON;
    const int tid = threadIdx.x;
    const int lane = tid & 63;
    const int wid = tid >> 6;
    const int wm = wid & 1;
    const int wn = wid >> 1;
    const int lr = lane & 15;
    const int kq = lane >> 4;

    f32x4 acc[2][2];
#pragma unroll
    for (int i = 0; i < 2; ++i)
#pragma unroll
        for (int j = 0; j < 2; ++j) acc[i][j] = (f32x4)0.0f;

    for (int k0 = 0; k0 < DD; k0 += OK) {
#pragma unroll
        for (int i = 0; i < 2; ++i) {
            int t2 = i * 256 + tid;
            int br = t2 >> 3;
            int cs = (t2 & 7) ^ (br & 7);
            __builtin_amdgcn_global_load_lds(
                (const __attribute__((address_space(1))) unsigned*)(W + (size_t)(bn + br) * DD + k0 + (cs << 3)),
                (__attribute__((address_space(3))) unsigned*)&Bs[t2 * 8], 16, 0, 0);
        }
        int hh = k0 >> 6;
#pragma unroll
        for (int i = 0; i < 2; ++i) {
            int t2 = i * 256 + tid;
            int ar = t2 >> 3;
            int p = t2 & 7;
            int d0 = (p ^ (ar & 7)) << 3;
            int grow = bm + ar;
            int b = grow >> 10;
            int s = grow & 1023;
            int hrow = ((b * HH + hh) << 10) + s;
            float m1 = Mp[hrow], m2 = Mp[NROW + hrow];
            float l1 = Lp[hrow], l2 = Lp[NROW + hrow];
            float m = fmaxf(m1, m2);
            float a1 = v_exp2(m1 - m), a2 = v_exp2(m2 - m);
            float inv = 1.0f / (l1 * a1 + l2 * a2);
            float c1 = a1 * inv, c2 = a2 * inv;
            bf16x8 o1 = *(const bf16x8*)&Op[(size_t)hrow * HDD + d0];
            bf16x8 o2 = *(const bf16x8*)&Op[((size_t)NROW + hrow) * HDD + d0];
            bf16x8 av;
#pragma unroll
            for (int e = 0; e < 8; ++e)
                av[e] = f2bf(bf2f(o1[e]) * c1 + bf2f(o2[e]) * c2);
            *(bf16x8*)&As[t2 * 8] = av;
        }
        __syncthreads();

        bf16x8 af[2][2], bfr[2][2];
#pragma unroll
        for (int f = 0; f < 2; ++f) {
            int rowa = wm * 32 + f * 16 + lr;
            int rowb = wn * 32 + f * 16 + lr;
#pragma unroll
            for (int ks = 0; ks < 2; ++ks) {
                int ca = (((ks << 2) | kq)) ^ (rowa & 7);
                int cb = (((ks << 2) | kq)) ^ (rowb & 7);
                af[f][ks] = *(const bf16x8*)&As[rowa * OK + (ca << 3)];
                bfr[f][ks] = *(const bf16x8*)&Bs[rowb * OK + (cb << 3)];
            }
        }
#pragma unroll
        for (int fm = 0; fm < 2; ++fm)
#pragma unroll
            for (int fn = 0; fn < 2; ++fn)
#pragma unroll
                for (int ks = 0; ks < 2; ++ks)
                    acc[fm][fn] = __builtin_amdgcn_mfma_f32_16x16x32_bf16(
                        af[fm][ks], bfr[fn][ks], acc[fm][fn], 0, 0, 0);
        __syncthreads();
    }

#pragma unroll
    for (int fm = 0; fm < 2; ++fm) {
        int row0 = bm + wm * 32 + fm * 16 + kq * 4;
#pragma unroll
        for (int fn = 0; fn < 2; ++fn) {
            int col = bn + wn * 32 + fn * 16 + lr;
            float bv_ = bias[col];
#pragma unroll
            for (int j = 0; j < 4; ++j)
                C[(size_t)(row0 + j) * DD + col] = acc[fm][fn][j] + bv_;
        }
    }
}

// ---------------------------------------------------------------------------
// MFMA flash attention — R11 base + T15 att[2] double-pipeline:
// QK^T(it+1) issued (ds_read + MFMA, non-blocking) BEFORE finish(it)
// (softmax+pack+PV on VALU) -> MFMA pipe fills under the softmax chain.
// 4-buffer LDS ring (64 KB), depth-2 prefetch, ONE vmcnt(4)+barrier per tile.
// Static A/B S-register sets (rule #20: no runtime-indexed state).
// Buffer safety: lead wave's stage(it+2) writes buf (it+2)&3 while trailing
// waves read at most bufs it&3 (V) and (it+1)&3 (qk of prior step) -> disjoint;
// readers of buf (it+2)&3 (tile it-2) completed before barrier(it-1) which
// all waves passed before any stage(it+2).
// ---------------------------------------------------------------------------
__global__ __launch_bounds__(256) void k_attn(
    const short* __restrict__ qb, const short* __restrict__ kb,
    const short* __restrict__ vt, const float* __restrict__ mask,
    short* __restrict__ Op, float* __restrict__ Mp, float* __restrict__ Lp) {
    __shared__ __align__(16) short Kls[4][64 * 64];   // 32 KB
    __shared__ __align__(16) short Vls[4][64 * 64];   // 32 KB

    const int bh = blockIdx.y;
    const int b = bh >> 4;
    const int h = bh & 15;
    const int q0 = blockIdx.x << 7;
    const int kvh = blockIdx.z;
    const int tbase = kvh << 9;          // 0 or 512
    const int tid = threadIdx.x;
    const int lane = tid & 63;
    const int w = tid >> 6;
    const int ql = lane & 31;
    const int hi = lane >> 5;
    const int rsw = ql & 7;
    const float scale2 = 0.125f * LOG2E;
    const float mval2 = MASK_VAL * LOG2E;

    const short* khead = kb + (size_t)b * SS * DD + h * HDD;
    const short* vhead = vt + (size_t)bh * HDD * SS;
    const float* maskp = mask + b * SS;

    bf16x8 qf0, qf1, qf2, qf3;
    {
        const short* qrow = qb + ((size_t)(b * SS + q0 + w * 32 + ql)) * DD + h * HDD + hi * 8;
        qf0 = *(const bf16x8*)(qrow);
        qf1 = *(const bf16x8*)(qrow + 16);
        qf2 = *(const bf16x8*)(qrow + 32);
        qf3 = *(const bf16x8*)(qrow + 48);
    }

    auto stage = [&](int t0, int bi) {
        const short* kbase = khead + (size_t)t0 * DD;
        const short* vbase = vhead + t0;
#pragma unroll
        for (int i = 0; i < 2; ++i) {
            int t = i * 256 + tid;
            int r = t >> 3;
            int cs = (t & 7) ^ (r & 7);
            __builtin_amdgcn_global_load_lds(
                (const __attribute__((address_space(1))) unsigned*)(kbase + (size_t)r * DD + cs * 8),
                (__attribute__((address_space(3))) unsigned*)&Kls[bi][t * 8], 16, 0, 0);
        }
#pragma unroll
        for (int i = 0; i < 2; ++i) {
            int t = i * 256 + tid;
            int r = t >> 3;
            int cs = (t & 7) ^ (r & 7);
            __builtin_amdgcn_global_load_lds(
                (const __attribute__((address_space(1))) unsigned*)(vbase + (size_t)r * SS + cs * 8),
                (__attribute__((address_space(3))) unsigned*)&Vls[bi][t * 8], 16, 0, 0);
        }
    };

    float m_r = -3.0e38f, l_r = 0.0f;
    f32x16 O0 = (f32x16)0.0f, O1 = (f32x16)0.0f;

    // issue QK^T for one tile: ds_read K + 8 MFMA into (s0,s1)
    auto qk = [&](const short* Kb, f32x16& s0, f32x16& s1) {
        s0 = (f32x16)0.0f; s1 = (f32x16)0.0f;
        __builtin_amdgcn_s_setprio(1);
#pragma unroll
        for (int step = 0; step < 4; ++step) {
            int cpos = ((step << 1) | hi) ^ rsw;
            bf16x8 k0 = *(const bf16x8*)&Kb[ql * 64 + (cpos << 3)];
            bf16x8 k1 = *(const bf16x8*)&Kb[(32 + ql) * 64 + (cpos << 3)];
            bf16x8 qf = (step == 0) ? qf0 : (step == 1) ? qf1 : (step == 2) ? qf2 : qf3;
            s0 = __builtin_amdgcn_mfma_f32_32x32x16_bf16(k0, qf, s0, 0, 0, 0);
            s1 = __builtin_amdgcn_mfma_f32_32x32x16_bf16(k1, qf, s1, 0, 0, 0);
        }
        __builtin_amdgcn_s_setprio(0);
    };

    // finish one tile: mask+softmax+pack+PV (V(t0) already resident)
    auto finish = [&](int t0, const short* Vb, f32x16& s0, f32x16& s1) {
#pragma unroll
        for (int g = 0; g < 4; ++g) {
            float4 a4 = *(const float4*)&maskp[t0 + 8 * g + 4 * hi];
            float4 b4 = *(const float4*)&maskp[t0 + 32 + 8 * g + 4 * hi];
            s0[4 * g + 0] = fmaf(s0[4 * g + 0], scale2, (1.0f - a4.x) * mval2);
            s0[4 * g + 1] = fmaf(s0[4 * g + 1], scale2, (1.0f - a4.y) * mval2);
            s0[4 * g + 2] = fmaf(s0[4 * g + 2], scale2, (1.0f - a4.z) * mval2);
            s0[4 * g + 3] = fmaf(s0[4 * g + 3], scale2, (1.0f - a4.w) * mval2);
            s1[4 * g + 0] = fmaf(s1[4 * g + 0], scale2, (1.0f - b4.x) * mval2);
            s1[4 * g + 1] = fmaf(s1[4 * g + 1], scale2, (1.0f - b4.y) * mval2);
            s1[4 * g + 2] = fmaf(s1[4 * g + 2], scale2, (1.0f - b4.z) * mval2);
            s1[4 * g + 3] = fmaf(s1[4 * g + 3], scale2, (1.0f - b4.w) * mval2);
        }

        float mt[16];
#pragma unroll
        for (int r = 0; r < 16; ++r) mt[r] = fmaxf(s0[r], s1[r]);
#pragma unroll
        for (int st = 8; st > 0; st >>= 1)
#pragma unroll
            for (int r = 0; r < 8; ++r)
                if (r < st) mt[r] = fmaxf(mt[r], mt[r + st]);
        float mx = fmaxf(mt[0], __shfl_xor(mt[0], 32));

        bool need = mx > m_r + 8.0f;   // exp2 domain
        if (__any(need)) {
            float mn = fmaxf(m_r, mx);
            float alpha = v_exp2(m_r - mn);
            m_r = mn;
            l_r *= alpha;
#pragma unroll
            for (int r = 0; r < 16; ++r) {
                int qrow = (r & 3) + 8 * (r >> 2) + 4 * hi;
                float al = __shfl(alpha, qrow, 64);
                O0[r] *= al;
                O1[r] *= al;
            }
        }

        float st0[16];
#pragma unroll
        for (int r = 0; r < 16; ++r) {
            s0[r] = v_exp2(s0[r] - m_r);
            s1[r] = v_exp2(s1[r] - m_r);
            st0[r] = s0[r] + s1[r];
        }
#pragma unroll
        for (int st = 8; st > 0; st >>= 1)
#pragma unroll
            for (int r = 0; r < 8; ++r)
                if (r < st) st0[r] += st0[r + st];
        l_r += st0[0] + __shfl_xor(st0[0], 32);

        unsigned w0 = cvt_pk_bf16(s0[0], s0[1]),  w1 = cvt_pk_bf16(s0[2], s0[3]);
        unsigned w2 = cvt_pk_bf16(s0[4], s0[5]),  w3 = cvt_pk_bf16(s0[6], s0[7]);
        unsigned w4 = cvt_pk_bf16(s0[8], s0[9]),  w5 = cvt_pk_bf16(s0[10], s0[11]);
        unsigned w6 = cvt_pk_bf16(s0[12], s0[13]), w7 = cvt_pk_bf16(s0[14], s0[15]);
        plane32_swap(w0, w2); plane32_swap(w1, w3);
        plane32_swap(w4, w6); plane32_swap(w5, w7);
        uint4v f0 = {w0, w1, w2, w3};
        uint4v f1 = {w4, w5, w6, w7};
        unsigned x0 = cvt_pk_bf16(s1[0], s1[1]),  x1 = cvt_pk_bf16(s1[2], s1[3]);
        unsigned x2 = cvt_pk_bf16(s1[4], s1[5]),  x3 = cvt_pk_bf16(s1[6], s1[7]);
        unsigned x4 = cvt_pk_bf16(s1[8], s1[9]),  x5 = cvt_pk_bf16(s1[10], s1[11]);
        unsigned x6 = cvt_pk_bf16(s1[12], s1[13]), x7 = cvt_pk_bf16(s1[14], s1[15]);
        plane32_swap(x0, x2); plane32_swap(x1, x3);
        plane32_swap(x4, x6); plane32_swap(x5, x7);
        uint4v f2 = {x0, x1, x2, x3};
        uint4v f3 = {x4, x5, x6, x7};

        bf16x8 pf0 = __builtin_bit_cast(bf16x8, f0);
        bf16x8 pf1 = __builtin_bit_cast(bf16x8, f1);
        bf16x8 pf2 = __builtin_bit_cast(bf16x8, f2);
        bf16x8 pf3 = __builtin_bit_cast(bf16x8, f3);

        __builtin_amdgcn_s_setprio(1);
#pragma unroll
        for (int ks = 0; ks < 4; ++ks) {
            int cpos = ((ks << 1) | hi) ^ rsw;
            bf16x8 pf = (ks == 0) ? pf0 : (ks == 1) ? pf1 : (ks == 2) ? pf2 : pf3;
            bf16x8 v0 = *(const bf16x8*)&Vb[ql * 64 + (cpos << 3)];
            bf16x8 v1 = *(const bf16x8*)&Vb[(32 + ql) * 64 + (cpos << 3)];
            O0 = __builtin_amdgcn_mfma_f32_32x32x16_bf16(pf, v0, O0, 0, 0, 0);
            O1 = __builtin_amdgcn_mfma_f32_32x32x16_bf16(pf, v1, O1, 0, 0, 0);
        }
        __builtin_amdgcn_s_setprio(0);
    };

    f32x16 A0, A1, B0, B1;

    // prologue: depth-2 prefetch
    stage(tbase, 0);
    stage(tbase + 64, 1);
    asm volatile("s_waitcnt vmcnt(4)\n\ts_barrier" ::: "memory");   // stage(0)+qf done
    qk(&Kls[0][0], A0, A1);

    // it=0
    stage(tbase + (2 << 6), 2);
    asm volatile("s_waitcnt vmcnt(4)\n\ts_barrier" ::: "memory");   // stage(1) done
    qk(&Kls[1][0], B0, B1);
    finish(tbase + (0 << 6), &Vls[0][0], A0, A1);
    // it=1
    stage(tbase + (3 << 6), 3);
    asm volatile("s_waitcnt vmcnt(4)\n\ts_barrier" ::: "memory");   // stage(2) done
    qk(&Kls[2][0], A0, A1);
    finish(tbase + (1 << 6), &Vls[1][0], B0, B1);
    // it=2
    stage(tbase + (4 << 6), 0);
    asm volatile("s_waitcnt vmcnt(4)\n\ts_barrier" ::: "memory");   // stage(3) done
    qk(&Kls[3][0], B0, B1);
    finish(tbase + (2 << 6), &Vls[2][0], A0, A1);
    // it=3
    stage(tbase + (5 << 6), 1);
    asm volatile("s_waitcnt vmcnt(4)\n\ts_barrier" ::: "memory");   // stage(4) done
    qk(&Kls[0][0], A0, A1);
    finish(tbase + (3 << 6), &Vls[3][0], B0, B1);
    // it=4
    stage(tbase + (6 << 6), 2);
    asm volatile("s_waitcnt vmcnt(4)\n\ts_barrier" ::: "memory");   // stage(5) done
    qk(&Kls[1][0], B0, B1);
    finish(tbase + (4 << 6), &Vls[0][0], A0, A1);
    // it=5
    stage(tbase + (7 << 6), 3);
    asm volatile("s_waitcnt vmcnt(4)\n\ts_barrier" ::: "memory");   // stage(6) done
    qk(&Kls[2][0], A0, A1);
    finish(tbase + (5 << 6), &Vls[1][0], B0, B1);
    // it=6 (no more stages)
    asm volatile("s_waitcnt vmcnt(0)\n\ts_barrier" ::: "memory");   // stage(7) done
    qk(&Kls[3][0], B0, B1);
    finish(tbase + (6 << 6), &Vls[2][0], A0, A1);
    // it=7
    finish(tbase + (7 << 6), &Vls[3][0], B0, B1);

    const int rowb = bh * SS + q0 + w * 32;
    short* ob = Op + ((size_t)kvh * NROW + rowb) * HDD;
#pragma unroll
    for (int r = 0; r < 16; ++r) {
        int qrow = (r & 3) + 8 * (r >> 2) + 4 * hi;
        ob[(size_t)qrow * HDD + ql] = f2bf(O0[r]);
        ob[(size_t)qrow * HDD + 32 + ql] = f2bf(O1[r]);
    }
    if (lane < 32) {
        Mp[kvh * NROW + rowb + lane] = m_r;
        Lp[kvh * NROW + rowb + lane] = l_r;
    }
}

// ---------------------------------------------------------------------------
extern "C" void kernel_launch(void* const* d_in, const int* in_sizes, int n_in,
                              void* d_out, int out_size, void* d_ws, size_t ws_size,
                              hipStream_t stream) {
    const float* h    = (const float*)d_in[0];
    const float* mask = (const float*)d_in[1];
    const float* wq   = (const float*)d_in[2];
    const float* bq   = (const float*)d_in[3];
    const float* wk   = (const float*)d_in[4];
    const float* bk   = (const float*)d_in[5];
    const float* wv   = (const float*)d_in[6];
    const float* bv   = (const float*)d_in[7];
    const float* wo   = (const float*)d_in[8];
    const float* bo   = (const float*)d_in[9];
    float* out = (float*)d_out;

    char* base = (char*)d_ws;
    short* x_bf  = (short*)base;                       // 4 MB @ 0
    short* w_bf  = (short*)(base + (4u << 20));        // 8 MB @ 4
    short* q_bf  = (short*)(base + (12u << 20));       // 4 MB @ 12
    short* k_bf  = (short*)(base + (16u << 20));       // 4 MB @ 16
    short* v_t   = (short*)(base + (20u << 20));       // 4 MB @ 20
    short* Op    = (short*)(base + (24u << 20));       // 8 MB @ 24
    float* Mp    = (float*)(base + (40u << 20));       // 256 KB
    float* Lp    = (float*)(base + (40u << 20) + (NKV * NROW * sizeof(float)));

    k_prep<<<3072, 256, 0, stream>>>(h, wq, wk, wv, wo, x_bf, w_bf);

    dim3 gqkv(DD / QBN, BB * SS / QBM, 3);
    k_gemm_qkv<<<gqkv, 256, 0, stream>>>(x_bf, w_bf, bq, bk, bv, q_bf, k_bf, v_t);

    dim3 gattn(SS / 128, BB * HH, NKV);
    k_attn<<<gattn, 256, 0, stream>>>(q_bf, k_bf, v_t, mask, Op, Mp, Lp);

    dim3 gout(DD / ON, BB * SS / OM);
    k_gemm_out_fused<<<gout, 256, 0, stream>>>(Op, Mp, Lp, w_bf + (size_t)3 * DD * DD, bo, out);
}

// Round 17
// 66.497 us; speedup vs baseline: 1.1251x; 1.1076x over previous
//
#include <hip/hip_runtime.h>
#include <hip/hip_bf16.h>

#define BB 2
#define SS 1024
#define DD 1024
#define HH 16
#define HDD 64
#define MASK_VAL -10000.0f
#define LOG2E 1.44269504f
#define BSD (BB * SS * DD)   // 2097152

typedef __attribute__((ext_vector_type(8))) short bf16x8;
typedef __attribute__((ext_vector_type(4))) short short4v;
typedef __attribute__((ext_vector_type(4))) float f32x4;
typedef __attribute__((ext_vector_type(16))) float f32x16;
typedef __attribute__((ext_vector_type(4))) unsigned int uint4v;

__device__ __forceinline__ short f2bf(float f) {
    union { float f; unsigned u; } v; v.f = f;
    unsigned r = v.u + 0x7FFFu + ((v.u >> 16) & 1u);   // RN-even
    return (short)(r >> 16);
}
__device__ __forceinline__ float bf2f(short s) {
    union { unsigned u; float f; } v;
    v.u = ((unsigned)(unsigned short)s) << 16;
    return v.f;
}
__device__ __forceinline__ unsigned cvt_pk_bf16(float lo, float hi) {
    unsigned r;
    asm("v_cvt_pk_bf16_f32 %0, %1, %2" : "=v"(r) : "v"(lo), "v"(hi));
    return r;
}
// bare v_exp_f32: computes 2^x (exp2 domain; log2e pre-folded into operands)
__device__ __forceinline__ float v_exp2(float x) {
    float r;
    asm("v_exp_f32 %0, %1" : "=v"(r) : "v"(x));
    return r;
}
__device__ __forceinline__ void plane32_swap(unsigned& a, unsigned& b) {
#if __has_builtin(__builtin_amdgcn_permlane32_swap)
    auto r = __builtin_amdgcn_permlane32_swap(a, b, false, false);
    a = r[0]; b = r[1];
#else
    unsigned as = (unsigned)__shfl_xor((int)a, 32);
    unsigned bs = (unsigned)__shfl_xor((int)b, 32);
    bool lo = ((threadIdx.x & 63) < 32);
    unsigned na = lo ? a : bs;
    unsigned nb = lo ? as : b;
    a = na; b = nb;
#endif
}

// ---------------------------------------------------------------------------
// fused prep, compact grid (3072 blocks)
// ---------------------------------------------------------------------------
__global__ __launch_bounds__(256) void k_prep(
    const float* __restrict__ h,
    const float* __restrict__ wq, const float* __restrict__ wk,
    const float* __restrict__ wv, const float* __restrict__ wo,
    short* __restrict__ xbf, short* __restrict__ wbf) {
    int id = blockIdx.x;
    if (id < 1024) {
        int i = id * 256 + threadIdx.x;
        const float4* h0 = (const float4*)h;
        const float4* h1 = (const float4*)(h + (size_t)BSD);
        float4 a0 = h0[2 * i], a1 = h0[2 * i + 1];
        float4 b0 = h1[2 * i], b1 = h1[2 * i + 1];
        bf16x8 o;
        o[0] = f2bf(a0.x + b0.x); o[1] = f2bf(a0.y + b0.y);
        o[2] = f2bf(a0.z + b0.z); o[3] = f2bf(a0.w + b0.w);
        o[4] = f2bf(a1.x + b1.x); o[5] = f2bf(a1.y + b1.y);
        o[6] = f2bf(a1.z + b1.z); o[7] = f2bf(a1.w + b1.w);
        ((bf16x8*)xbf)[i] = o;
    } else {
        int zi = (id - 1024) >> 9;
        int i = ((id - 1024) & 511) * 256 + threadIdx.x;
        const float* src = (zi == 0) ? wq : (zi == 1) ? wk : (zi == 2) ? wv : wo;
        short* dst = wbf + (size_t)zi * (DD * DD);
        const float4* s4 = (const float4*)src;
        float4 a0 = s4[2 * i], a1 = s4[2 * i + 1];
        bf16x8 o;
        o[0] = f2bf(a0.x); o[1] = f2bf(a0.y); o[2] = f2bf(a0.z); o[3] = f2bf(a0.w);
        o[4] = f2bf(a1.x); o[5] = f2bf(a1.y); o[6] = f2bf(a1.z); o[7] = f2bf(a1.w);
        ((bf16x8*)dst)[i] = o;
    }
}

// ---------------------------------------------------------------------------
// QKV bf16 MFMA GEMM — R14-exact (best measured): 128x64 tile, BK=64,
// XOR chunk-swizzled LDS, single-buffer 2-barrier loop.
// ---------------------------------------------------------------------------
#define QBM 128
#define QBN 64
#define QBK 64

__global__ __launch_bounds__(256) void k_gemm_qkv(
    const short* __restrict__ xbf, const short* __restrict__ wbf,
    const float* __restrict__ bq, const float* __restrict__ bk,
    const float* __restrict__ bv,
    short* __restrict__ qb, short* __restrict__ kb, short* __restrict__ vt) {
    __shared__ __align__(16) short As[QBM * QBK];   // 16 KB
    __shared__ __align__(16) short Bs[QBN * QBK];   // 8 KB
    const int z = blockIdx.z;
    const short* W = wbf + (size_t)z * (DD * DD);
    const float* bias = (z == 0) ? bq : (z == 1) ? bk : bv;
    const int bm = blockIdx.y * QBM;
    const int bn = blockIdx.x * QBN;
    const int tid = threadIdx.x;
    const int lane = tid & 63;
    const int wid = tid >> 6;
    const int wm = wid >> 1;
    const int wn = wid & 1;
    const int lr = lane & 15;
    const int kq = lane >> 4;

    f32x4 acc[4][2];
#pragma unroll
    for (int i = 0; i < 4; ++i)
#pragma unroll
        for (int j = 0; j < 2; ++j) acc[i][j] = (f32x4)0.0f;

    for (int k0 = 0; k0 < DD; k0 += QBK) {
#pragma unroll
        for (int i = 0; i < 4; ++i) {           // A: 128 rows x 64 k
            int s = i * 256 + tid;
            int r = s >> 3;
            int cs = (s & 7) ^ (r & 7);
            __builtin_amdgcn_global_load_lds(
                (const __attribute__((address_space(1))) unsigned*)(xbf + (size_t)(bm + r) * DD + k0 + (cs << 3)),
                (__attribute__((address_space(3))) unsigned*)&As[s * 8], 16, 0, 0);
        }
#pragma unroll
        for (int i = 0; i < 2; ++i) {           // B: 64 rows x 64 k
            int s = i * 256 + tid;
            int r = s >> 3;
            int cs = (s & 7) ^ (r & 7);
            __builtin_amdgcn_global_load_lds(
                (const __attribute__((address_space(1))) unsigned*)(W + (size_t)(bn + r) * DD + k0 + (cs << 3)),
                (__attribute__((address_space(3))) unsigned*)&Bs[s * 8], 16, 0, 0);
        }
        __syncthreads();

        bf16x8 af[4][2], bfr[2][2];
#pragma unroll
        for (int f = 0; f < 4; ++f) {
            int row = wm * 64 + f * 16 + lr;
#pragma unroll
            for (int ks = 0; ks < 2; ++ks) {
                int cpos = ((ks << 2) | kq) ^ (row & 7);
                af[f][ks] = *(const bf16x8*)&As[row * QBK + (cpos << 3)];
            }
        }
#pragma unroll
        for (int g = 0; g < 2; ++g) {
            int row = wn * 32 + g * 16 + lr;
#pragma unroll
            for (int ks = 0; ks < 2; ++ks) {
                int cpos = ((ks << 2) | kq) ^ (row & 7);
                bfr[g][ks] = *(const bf16x8*)&Bs[row * QBK + (cpos << 3)];
            }
        }
#pragma unroll
        for (int fm = 0; fm < 4; ++fm)
#pragma unroll
            for (int fn = 0; fn < 2; ++fn)
#pragma unroll
                for (int ks = 0; ks < 2; ++ks)
                    acc[fm][fn] = __builtin_amdgcn_mfma_f32_16x16x32_bf16(
                        af[fm][ks], bfr[fn][ks], acc[fm][fn], 0, 0, 0);
        __syncthreads();
    }

    if (z < 2) {
        short* C = (z == 0) ? qb : kb;
#pragma unroll
        for (int fm = 0; fm < 4; ++fm) {
            int row0 = bm + wm * 64 + fm * 16 + kq * 4;
#pragma unroll
            for (int fn = 0; fn < 2; ++fn) {
                int col = bn + wn * 32 + fn * 16 + lr;
                float bv_ = bias[col];
#pragma unroll
                for (int j = 0; j < 4; ++j)
                    C[(size_t)(row0 + j) * DD + col] = f2bf(acc[fm][fn][j] + bv_);
            }
        }
    } else {
#pragma unroll
        for (int fm = 0; fm < 4; ++fm) {
            int row0 = bm + wm * 64 + fm * 16 + kq * 4;
            int bidx = row0 >> 10, s0 = row0 & 1023;
#pragma unroll
            for (int fn = 0; fn < 2; ++fn) {
                int col = bn + wn * 32 + fn * 16 + lr;
                float bv_ = bias[col];
                size_t addr = ((size_t)(bidx * HH + (col >> 6)) * HDD + (col & 63)) * SS + s0;
                short4v o;
                o.x = f2bf(acc[fm][fn][0] + bv_); o.y = f2bf(acc[fm][fn][1] + bv_);
                o.z = f2bf(acc[fm][fn][2] + bv_); o.w = f2bf(acc[fm][fn][3] + bv_);
                *(short4v*)&vt[addr] = o;
            }
        }
    }
}

// ---------------------------------------------------------------------------
// Output GEMM — now a PLAIN swizzled GEMM (merge moved into k_attn).
// 64x64 tile, BK=64, 256 thr, XOR chunk-swizzle both tiles, f32 out + bias.
// grid (16,32) = 512 blocks = 2/CU.
// ---------------------------------------------------------------------------
#define OM 64
#define ON 64
#define OK 64

__global__ __launch_bounds__(256) void k_gemm_out(
    const short* __restrict__ A, const short* __restrict__ W,
    const float* __restrict__ bias, float* __restrict__ C) {
    __shared__ __align__(16) short As[OM * OK];   // 8 KB
    __shared__ __align__(16) short Bs[ON * OK];   // 8 KB
    const int bm = blockIdx.y * OM;
    const int bn = blockIdx.x * ON;
    const int tid = threadIdx.x;
    const int lane = tid & 63;
    const int wid = tid >> 6;
    const int wm = wid & 1;
    const int wn = wid >> 1;
    const int lr = lane & 15;
    const int kq = lane >> 4;

    f32x4 acc[2][2];
#pragma unroll
    for (int i = 0; i < 2; ++i)
#pragma unroll
        for (int j = 0; j < 2; ++j) acc[i][j] = (f32x4)0.0f;

    for (int k0 = 0; k0 < DD; k0 += OK) {
#pragma unroll
        for (int i = 0; i < 2; ++i) {
            int t2 = i * 256 + tid;
            int r = t2 >> 3;
            int cs = (t2 & 7) ^ (r & 7);
            __builtin_amdgcn_global_load_lds(
                (const __attribute__((address_space(1))) unsigned*)(A + (size_t)(bm + r) * DD + k0 + (cs << 3)),
                (__attribute__((address_space(3))) unsigned*)&As[t2 * 8], 16, 0, 0);
        }
#pragma unroll
        for (int i = 0; i < 2; ++i) {
            int t2 = i * 256 + tid;
            int r = t2 >> 3;
            int cs = (t2 & 7) ^ (r & 7);
            __builtin_amdgcn_global_load_lds(
                (const __attribute__((address_space(1))) unsigned*)(W + (size_t)(bn + r) * DD + k0 + (cs << 3)),
                (__attribute__((address_space(3))) unsigned*)&Bs[t2 * 8], 16, 0, 0);
        }
        __syncthreads();

        bf16x8 af[2][2], bfr[2][2];
#pragma unroll
        for (int f = 0; f < 2; ++f) {
            int rowa = wm * 32 + f * 16 + lr;
            int rowb = wn * 32 + f * 16 + lr;
#pragma unroll
            for (int ks = 0; ks < 2; ++ks) {
                int ca = (((ks << 2) | kq)) ^ (rowa & 7);
                int cb = (((ks << 2) | kq)) ^ (rowb & 7);
                af[f][ks] = *(const bf16x8*)&As[rowa * OK + (ca << 3)];
                bfr[f][ks] = *(const bf16x8*)&Bs[rowb * OK + (cb << 3)];
            }
        }
#pragma unroll
        for (int fm = 0; fm < 2; ++fm)
#pragma unroll
            for (int fn = 0; fn < 2; ++fn)
#pragma unroll
                for (int ks = 0; ks < 2; ++ks)
                    acc[fm][fn] = __builtin_amdgcn_mfma_f32_16x16x32_bf16(
                        af[fm][ks], bfr[fn][ks], acc[fm][fn], 0, 0, 0);
        __syncthreads();
    }

#pragma unroll
    for (int fm = 0; fm < 2; ++fm) {
        int row0 = bm + wm * 32 + fm * 16 + kq * 4;
#pragma unroll
        for (int fn = 0; fn < 2; ++fn) {
            int col = bn + wn * 32 + fn * 16 + lr;
            float bv_ = bias[col];
#pragma unroll
            for (int j = 0; j < 4; ++j)
                C[(size_t)(row0 + j) * DD + col] = acc[fm][fn][j] + bv_;
        }
    }
}

// ---------------------------------------------------------------------------
// MFMA flash attention — fused split-KV: 512 thr = 8 waves; waves 0-3 process
// kv[0,512), waves 4-7 kv[512,1024) over the SAME 128 q-rows (symmetric work,
// lockstep barriers). Body = R11-exact (best measured). Final merge in-LDS
// in fp32 (kvh=1 deposits O/m/l -> barrier -> kvh=0 combines, writes ctx bf16)
// — eliminates the Op/Mp/Lp global round-trip entirely.
// ---------------------------------------------------------------------------
__global__ __launch_bounds__(512) void k_attn(
    const short* __restrict__ qb, const short* __restrict__ kb,
    const short* __restrict__ vt, const float* __restrict__ mask,
    short* __restrict__ ctx) {
    __shared__ __align__(16) short Kls[2][2][64 * 64];   // [kvh][dbuf] 32 KB
    __shared__ __align__(16) short Vls[2][2][64 * 64];   // 32 KB

    const int bh = blockIdx.y;
    const int b = bh >> 4;
    const int h = bh & 15;
    const int q0 = blockIdx.x << 7;
    const int tid = threadIdx.x;
    const int gtid = tid & 255;          // thread within kv-group
    const int kvh = tid >> 8;            // 0 or 1
    const int lane = tid & 63;
    const int w4 = (tid >> 6) & 3;       // wave within group: q sub-tile
    const int ql = lane & 31;
    const int hi = lane >> 5;
    const int rsw = ql & 7;
    const int tbase = kvh << 9;          // 0 or 512
    const float scale2 = 0.125f * LOG2E;
    const float mval2 = MASK_VAL * LOG2E;

    const short* khead = kb + (size_t)b * SS * DD + h * HDD;
    const short* vhead = vt + (size_t)bh * HDD * SS;
    const float* maskp = mask + b * SS;

    bf16x8 qf0, qf1, qf2, qf3;
    {
        const short* qrow = qb + ((size_t)(b * SS + q0 + w4 * 32 + ql)) * DD + h * HDD + hi * 8;
        qf0 = *(const bf16x8*)(qrow);
        qf1 = *(const bf16x8*)(qrow + 16);
        qf2 = *(const bf16x8*)(qrow + 32);
        qf3 = *(const bf16x8*)(qrow + 48);
    }

    auto stage = [&](int t0, int bi) {
        const short* kbase = khead + (size_t)t0 * DD;
        const short* vbase = vhead + t0;
#pragma unroll
        for (int i = 0; i < 2; ++i) {
            int t = i * 256 + gtid;
            int r = t >> 3;
            int cs = (t & 7) ^ (r & 7);
            __builtin_amdgcn_global_load_lds(
                (const __attribute__((address_space(1))) unsigned*)(kbase + (size_t)r * DD + cs * 8),
                (__attribute__((address_space(3))) unsigned*)&Kls[kvh][bi][t * 8], 16, 0, 0);
        }
#pragma unroll
        for (int i = 0; i < 2; ++i) {
            int t = i * 256 + gtid;
            int r = t >> 3;
            int cs = (t & 7) ^ (r & 7);
            __builtin_amdgcn_global_load_lds(
                (const __attribute__((address_space(1))) unsigned*)(vbase + (size_t)r * SS + cs * 8),
                (__attribute__((address_space(3))) unsigned*)&Vls[kvh][bi][t * 8], 16, 0, 0);
        }
    };

    float m_r = -3.0e38f, l_r = 0.0f;
    f32x16 O0 = (f32x16)0.0f, O1 = (f32x16)0.0f;

    auto body = [&](int t0, int cur, int tail) {
        const short* Kb = &Kls[kvh][cur][0];
        const short* Vb = &Vls[kvh][cur][0];

        f32x16 s0 = (f32x16)0.0f, s1 = (f32x16)0.0f;
        __builtin_amdgcn_s_setprio(1);
#pragma unroll
        for (int step = 0; step < 4; ++step) {
            int cpos = ((step << 1) | hi) ^ rsw;
            bf16x8 k0 = *(const bf16x8*)&Kb[ql * 64 + (cpos << 3)];
            bf16x8 k1 = *(const bf16x8*)&Kb[(32 + ql) * 64 + (cpos << 3)];
            bf16x8 qf = (step == 0) ? qf0 : (step == 1) ? qf1 : (step == 2) ? qf2 : qf3;
            s0 = __builtin_amdgcn_mfma_f32_32x32x16_bf16(k0, qf, s0, 0, 0, 0);
            s1 = __builtin_amdgcn_mfma_f32_32x32x16_bf16(k1, qf, s1, 0, 0, 0);
        }
        __builtin_amdgcn_s_setprio(0);

#pragma unroll
        for (int g = 0; g < 4; ++g) {
            float4 a4 = *(const float4*)&maskp[t0 + 8 * g + 4 * hi];
            float4 b4 = *(const float4*)&maskp[t0 + 32 + 8 * g + 4 * hi];
            s0[4 * g + 0] = fmaf(s0[4 * g + 0], scale2, (1.0f - a4.x) * mval2);
            s0[4 * g + 1] = fmaf(s0[4 * g + 1], scale2, (1.0f - a4.y) * mval2);
            s0[4 * g + 2] = fmaf(s0[4 * g + 2], scale2, (1.0f - a4.z) * mval2);
            s0[4 * g + 3] = fmaf(s0[4 * g + 3], scale2, (1.0f - a4.w) * mval2);
            s1[4 * g + 0] = fmaf(s1[4 * g + 0], scale2, (1.0f - b4.x) * mval2);
            s1[4 * g + 1] = fmaf(s1[4 * g + 1], scale2, (1.0f - b4.y) * mval2);
            s1[4 * g + 2] = fmaf(s1[4 * g + 2], scale2, (1.0f - b4.z) * mval2);
            s1[4 * g + 3] = fmaf(s1[4 * g + 3], scale2, (1.0f - b4.w) * mval2);
        }

        float mt[16];
#pragma unroll
        for (int r = 0; r < 16; ++r) mt[r] = fmaxf(s0[r], s1[r]);
#pragma unroll
        for (int st = 8; st > 0; st >>= 1)
#pragma unroll
            for (int r = 0; r < 8; ++r)
                if (r < st) mt[r] = fmaxf(mt[r], mt[r + st]);
        float mx = fmaxf(mt[0], __shfl_xor(mt[0], 32));

        bool need = mx > m_r + 8.0f;   // exp2 domain: P bounded by 2^8
        if (__any(need)) {
            float mn = fmaxf(m_r, mx);
            float alpha = v_exp2(m_r - mn);
            m_r = mn;
            l_r *= alpha;
#pragma unroll
            for (int r = 0; r < 16; ++r) {
                int qrow = (r & 3) + 8 * (r >> 2) + 4 * hi;
                float al = __shfl(alpha, qrow, 64);
                O0[r] *= al;
                O1[r] *= al;
            }
        }

        float st0[16];
#pragma unroll
        for (int r = 0; r < 16; ++r) {
            s0[r] = v_exp2(s0[r] - m_r);
            s1[r] = v_exp2(s1[r] - m_r);
            st0[r] = s0[r] + s1[r];
        }
#pragma unroll
        for (int st = 8; st > 0; st >>= 1)
#pragma unroll
            for (int r = 0; r < 8; ++r)
                if (r < st) st0[r] += st0[r + st];
        l_r += st0[0] + __shfl_xor(st0[0], 32);

        unsigned w0 = cvt_pk_bf16(s0[0], s0[1]),  w1 = cvt_pk_bf16(s0[2], s0[3]);
        unsigned w2 = cvt_pk_bf16(s0[4], s0[5]),  w3 = cvt_pk_bf16(s0[6], s0[7]);
        unsigned w4_ = cvt_pk_bf16(s0[8], s0[9]),  w5 = cvt_pk_bf16(s0[10], s0[11]);
        unsigned w6 = cvt_pk_bf16(s0[12], s0[13]), w7 = cvt_pk_bf16(s0[14], s0[15]);
        plane32_swap(w0, w2); plane32_swap(w1, w3);
        plane32_swap(w4_, w6); plane32_swap(w5, w7);
        uint4v f0 = {w0, w1, w2, w3};
        uint4v f1 = {w4_, w5, w6, w7};
        unsigned x0 = cvt_pk_bf16(s1[0], s1[1]),  x1 = cvt_pk_bf16(s1[2], s1[3]);
        unsigned x2 = cvt_pk_bf16(s1[4], s1[5]),  x3 = cvt_pk_bf16(s1[6], s1[7]);
        unsigned x4 = cvt_pk_bf16(s1[8], s1[9]),  x5 = cvt_pk_bf16(s1[10], s1[11]);
        unsigned x6 = cvt_pk_bf16(s1[12], s1[13]), x7 = cvt_pk_bf16(s1[14], s1[15]);
        plane32_swap(x0, x2); plane32_swap(x1, x3);
        plane32_swap(x4, x6); plane32_swap(x5, x7);
        uint4v f2 = {x0, x1, x2, x3};
        uint4v f3 = {x4, x5, x6, x7};

        bf16x8 pf0 = __builtin_bit_cast(bf16x8, f0);
        bf16x8 pf1 = __builtin_bit_cast(bf16x8, f1);
        bf16x8 pf2 = __builtin_bit_cast(bf16x8, f2);
        bf16x8 pf3 = __builtin_bit_cast(bf16x8, f3);

        if (tail) { asm volatile("s_waitcnt vmcnt(0)\n\ts_barrier" ::: "memory"); }
        else      { asm volatile("s_waitcnt vmcnt(4)\n\ts_barrier" ::: "memory"); }

        __builtin_amdgcn_s_setprio(1);
#pragma unroll
        for (int ks = 0; ks < 4; ++ks) {
            int cpos = ((ks << 1) | hi) ^ rsw;
            bf16x8 pf = (ks == 0) ? pf0 : (ks == 1) ? pf1 : (ks == 2) ? pf2 : pf3;
            bf16x8 v0 = *(const bf16x8*)&Vb[ql * 64 + (cpos << 3)];
            bf16x8 v1 = *(const bf16x8*)&Vb[(32 + ql) * 64 + (cpos << 3)];
            O0 = __builtin_amdgcn_mfma_f32_32x32x16_bf16(pf, v0, O0, 0, 0, 0);
            O1 = __builtin_amdgcn_mfma_f32_32x32x16_bf16(pf, v1, O1, 0, 0, 0);
        }
        __builtin_amdgcn_s_setprio(0);
    };

    stage(tbase, 0);
    for (int it = 0; it < 7; ++it) {
        stage(tbase + ((it + 1) << 6), (it + 1) & 1);
        asm volatile("s_waitcnt vmcnt(6)\n\ts_barrier" ::: "memory");   // K(it) ready
        body(tbase + (it << 6), it & 1, 0);
        asm volatile("s_barrier" ::: "memory");                         // buf reuse guard
    }
    asm volatile("s_waitcnt vmcnt(2)\n\ts_barrier" ::: "memory");       // K(7) ready
    body(tbase + (7 << 6), 1, 1);

    // ---- in-LDS fp32 merge of the two kv-halves ----
    __syncthreads();                                   // all K/V reads done
    float* osh = (float*)&Kls[0][0][0];                // 4 x 2048 floats (32 KB)
    float* mlsh = (float*)&Vls[0][0][0];               // 4 x 64 floats
    if (kvh == 1) {
        float* obuf = osh + w4 * 2048;
#pragma unroll
        for (int r = 0; r < 16; ++r) {
            int qrow = (r & 3) + 8 * (r >> 2) + 4 * hi;
            obuf[qrow * 64 + ql] = O0[r];
            obuf[qrow * 64 + 32 + ql] = O1[r];
        }
        if (lane < 32) {
            mlsh[w4 * 64 + ql] = m_r;
            mlsh[w4 * 64 + 32 + ql] = l_r;
        }
    }
    __syncthreads();
    if (kvh == 0) {
        float* obuf = osh + w4 * 2048;
        float m2 = mlsh[w4 * 64 + ql];
        float l2 = mlsh[w4 * 64 + 32 + ql];
        float m = fmaxf(m_r, m2);
        float a1 = v_exp2(m_r - m), a2 = v_exp2(m2 - m);
        float inv = 1.0f / (l_r * a1 + l2 * a2);
        float c1 = a1 * inv, c2 = a2 * inv;
        short* cb = ctx + ((size_t)(b * SS + q0 + w4 * 32)) * DD + h * HDD;
#pragma unroll
        for (int r = 0; r < 16; ++r) {
            int qrow = (r & 3) + 8 * (r >> 2) + 4 * hi;
            float cc1 = __shfl(c1, qrow, 64);
            float cc2 = __shfl(c2, qrow, 64);
            float ob0 = obuf[qrow * 64 + ql];
            float ob1 = obuf[qrow * 64 + 32 + ql];
            cb[(size_t)qrow * DD + ql]      = f2bf(O0[r] * cc1 + ob0 * cc2);
            cb[(size_t)qrow * DD + 32 + ql] = f2bf(O1[r] * cc1 + ob1 * cc2);
        }
    }
}

// ---------------------------------------------------------------------------
extern "C" void kernel_launch(void* const* d_in, const int* in_sizes, int n_in,
                              void* d_out, int out_size, void* d_ws, size_t ws_size,
                              hipStream_t stream) {
    const float* h    = (const float*)d_in[0];
    const float* mask = (const float*)d_in[1];
    const float* wq   = (const float*)d_in[2];
    const float* bq   = (const float*)d_in[3];
    const float* wk   = (const float*)d_in[4];
    const float* bk   = (const float*)d_in[5];
    const float* wv   = (const float*)d_in[6];
    const float* bv   = (const float*)d_in[7];
    const float* wo   = (const float*)d_in[8];
    const float* bo   = (const float*)d_in[9];
    float* out = (float*)d_out;

    char* base = (char*)d_ws;
    short* x_bf  = (short*)base;                       // 4 MB @ 0
    short* w_bf  = (short*)(base + (4u << 20));        // 8 MB @ 4
    short* q_bf  = (short*)(base + (12u << 20));       // 4 MB @ 12
    short* k_bf  = (short*)(base + (16u << 20));       // 4 MB @ 16
    short* v_t   = (short*)(base + (20u << 20));       // 4 MB @ 20
    short* ctxbf = (short*)(base + (24u << 20));       // 4 MB @ 24

    k_prep<<<3072, 256, 0, stream>>>(h, wq, wk, wv, wo, x_bf, w_bf);

    dim3 gqkv(DD / QBN, BB * SS / QBM, 3);
    k_gemm_qkv<<<gqkv, 256, 0, stream>>>(x_bf, w_bf, bq, bk, bv, q_bf, k_bf, v_t);

    dim3 gattn(SS / 128, BB * HH);
    k_attn<<<gattn, 512, 0, stream>>>(q_bf, k_bf, v_t, mask, ctxbf);

    dim3 gout(DD / ON, BB * SS / OM);
    k_gemm_out<<<gout, 256, 0, stream>>>(ctxbf, w_bf + (size_t)3 * DD * DD, bo, out);
}

// Round 18
// 64.483 us; speedup vs baseline: 1.1602x; 1.0312x over previous
//
#include <hip/hip_runtime.h>
#include <hip/hip_bf16.h>

#define BB 2
#define SS 1024
#define DD 1024
#define HH 16
#define HDD 64
#define MASK_VAL -10000.0f
#define LOG2E 1.44269504f
#define BSD (BB * SS * DD)   // 2097152

typedef __attribute__((ext_vector_type(8))) short bf16x8;
typedef __attribute__((ext_vector_type(4))) short short4v;
typedef __attribute__((ext_vector_type(4))) float f32x4;
typedef __attribute__((ext_vector_type(16))) float f32x16;
typedef __attribute__((ext_vector_type(4))) unsigned int uint4v;

__device__ __forceinline__ short f2bf(float f) {
    union { float f; unsigned u; } v; v.f = f;
    unsigned r = v.u + 0x7FFFu + ((v.u >> 16) & 1u);   // RN-even
    return (short)(r >> 16);
}
__device__ __forceinline__ float bf2f(short s) {
    union { unsigned u; float f; } v;
    v.u = ((unsigned)(unsigned short)s) << 16;
    return v.f;
}
__device__ __forceinline__ unsigned cvt_pk_bf16(float lo, float hi) {
    unsigned r;
    asm("v_cvt_pk_bf16_f32 %0, %1, %2" : "=v"(r) : "v"(lo), "v"(hi));
    return r;
}
// bare v_exp_f32: computes 2^x (exp2 domain; log2e pre-folded into operands)
__device__ __forceinline__ float v_exp2(float x) {
    float r;
    asm("v_exp_f32 %0, %1" : "=v"(r) : "v"(x));
    return r;
}
__device__ __forceinline__ void plane32_swap(unsigned& a, unsigned& b) {
#if __has_builtin(__builtin_amdgcn_permlane32_swap)
    auto r = __builtin_amdgcn_permlane32_swap(a, b, false, false);
    a = r[0]; b = r[1];
#else
    unsigned as = (unsigned)__shfl_xor((int)a, 32);
    unsigned bs = (unsigned)__shfl_xor((int)b, 32);
    bool lo = ((threadIdx.x & 63) < 32);
    unsigned na = lo ? a : bs;
    unsigned nb = lo ? as : b;
    a = na; b = nb;
#endif
}

// ---------------------------------------------------------------------------
// fused prep, compact grid (3072 blocks)
// ---------------------------------------------------------------------------
__global__ __launch_bounds__(256) void k_prep(
    const float* __restrict__ h,
    const float* __restrict__ wq, const float* __restrict__ wk,
    const float* __restrict__ wv, const float* __restrict__ wo,
    short* __restrict__ xbf, short* __restrict__ wbf) {
    int id = blockIdx.x;
    if (id < 1024) {
        int i = id * 256 + threadIdx.x;
        const float4* h0 = (const float4*)h;
        const float4* h1 = (const float4*)(h + (size_t)BSD);
        float4 a0 = h0[2 * i], a1 = h0[2 * i + 1];
        float4 b0 = h1[2 * i], b1 = h1[2 * i + 1];
        bf16x8 o;
        o[0] = f2bf(a0.x + b0.x); o[1] = f2bf(a0.y + b0.y);
        o[2] = f2bf(a0.z + b0.z); o[3] = f2bf(a0.w + b0.w);
        o[4] = f2bf(a1.x + b1.x); o[5] = f2bf(a1.y + b1.y);
        o[6] = f2bf(a1.z + b1.z); o[7] = f2bf(a1.w + b1.w);
        ((bf16x8*)xbf)[i] = o;
    } else {
        int zi = (id - 1024) >> 9;
        int i = ((id - 1024) & 511) * 256 + threadIdx.x;
        const float* src = (zi == 0) ? wq : (zi == 1) ? wk : (zi == 2) ? wv : wo;
        short* dst = wbf + (size_t)zi * (DD * DD);
        const float4* s4 = (const float4*)src;
        float4 a0 = s4[2 * i], a1 = s4[2 * i + 1];
        bf16x8 o;
        o[0] = f2bf(a0.x); o[1] = f2bf(a0.y); o[2] = f2bf(a0.z); o[3] = f2bf(a0.w);
        o[4] = f2bf(a1.x); o[5] = f2bf(a1.y); o[6] = f2bf(a1.z); o[7] = f2bf(a1.w);
        ((bf16x8*)dst)[i] = o;
    }
}

// ---------------------------------------------------------------------------
// QKV bf16 MFMA GEMM — R14-exact: 128x64 tile, BK=64, XOR chunk-swizzled LDS.
// ---------------------------------------------------------------------------
#define QBM 128
#define QBN 64
#define QBK 64

__global__ __launch_bounds__(256) void k_gemm_qkv(
    const short* __restrict__ xbf, const short* __restrict__ wbf,
    const float* __restrict__ bq, const float* __restrict__ bk,
    const float* __restrict__ bv,
    short* __restrict__ qb, short* __restrict__ kb, short* __restrict__ vt) {
    __shared__ __align__(16) short As[QBM * QBK];   // 16 KB
    __shared__ __align__(16) short Bs[QBN * QBK];   // 8 KB
    const int z = blockIdx.z;
    const short* W = wbf + (size_t)z * (DD * DD);
    const float* bias = (z == 0) ? bq : (z == 1) ? bk : bv;
    const int bm = blockIdx.y * QBM;
    const int bn = blockIdx.x * QBN;
    const int tid = threadIdx.x;
    const int lane = tid & 63;
    const int wid = tid >> 6;
    const int wm = wid >> 1;
    const int wn = wid & 1;
    const int lr = lane & 15;
    const int kq = lane >> 4;

    f32x4 acc[4][2];
#pragma unroll
    for (int i = 0; i < 4; ++i)
#pragma unroll
        for (int j = 0; j < 2; ++j) acc[i][j] = (f32x4)0.0f;

    for (int k0 = 0; k0 < DD; k0 += QBK) {
#pragma unroll
        for (int i = 0; i < 4; ++i) {
            int s = i * 256 + tid;
            int r = s >> 3;
            int cs = (s & 7) ^ (r & 7);
            __builtin_amdgcn_global_load_lds(
                (const __attribute__((address_space(1))) unsigned*)(xbf + (size_t)(bm + r) * DD + k0 + (cs << 3)),
                (__attribute__((address_space(3))) unsigned*)&As[s * 8], 16, 0, 0);
        }
#pragma unroll
        for (int i = 0; i < 2; ++i) {
            int s = i * 256 + tid;
            int r = s >> 3;
            int cs = (s & 7) ^ (r & 7);
            __builtin_amdgcn_global_load_lds(
                (const __attribute__((address_space(1))) unsigned*)(W + (size_t)(bn + r) * DD + k0 + (cs << 3)),
                (__attribute__((address_space(3))) unsigned*)&Bs[s * 8], 16, 0, 0);
        }
        __syncthreads();

        bf16x8 af[4][2], bfr[2][2];
#pragma unroll
        for (int f = 0; f < 4; ++f) {
            int row = wm * 64 + f * 16 + lr;
#pragma unroll
            for (int ks = 0; ks < 2; ++ks) {
                int cpos = ((ks << 2) | kq) ^ (row & 7);
                af[f][ks] = *(const bf16x8*)&As[row * QBK + (cpos << 3)];
            }
        }
#pragma unroll
        for (int g = 0; g < 2; ++g) {
            int row = wn * 32 + g * 16 + lr;
#pragma unroll
            for (int ks = 0; ks < 2; ++ks) {
                int cpos = ((ks << 2) | kq) ^ (row & 7);
                bfr[g][ks] = *(const bf16x8*)&Bs[row * QBK + (cpos << 3)];
            }
        }
#pragma unroll
        for (int fm = 0; fm < 4; ++fm)
#pragma unroll
            for (int fn = 0; fn < 2; ++fn)
#pragma unroll
                for (int ks = 0; ks < 2; ++ks)
                    acc[fm][fn] = __builtin_amdgcn_mfma_f32_16x16x32_bf16(
                        af[fm][ks], bfr[fn][ks], acc[fm][fn], 0, 0, 0);
        __syncthreads();
    }

    if (z < 2) {
        short* C = (z == 0) ? qb : kb;
#pragma unroll
        for (int fm = 0; fm < 4; ++fm) {
            int row0 = bm + wm * 64 + fm * 16 + kq * 4;
#pragma unroll
            for (int fn = 0; fn < 2; ++fn) {
                int col = bn + wn * 32 + fn * 16 + lr;
                float bv_ = bias[col];
#pragma unroll
                for (int j = 0; j < 4; ++j)
                    C[(size_t)(row0 + j) * DD + col] = f2bf(acc[fm][fn][j] + bv_);
            }
        }
    } else {
#pragma unroll
        for (int fm = 0; fm < 4; ++fm) {
            int row0 = bm + wm * 64 + fm * 16 + kq * 4;
            int bidx = row0 >> 10, s0 = row0 & 1023;
#pragma unroll
            for (int fn = 0; fn < 2; ++fn) {
                int col = bn + wn * 32 + fn * 16 + lr;
                float bv_ = bias[col];
                size_t addr = ((size_t)(bidx * HH + (col >> 6)) * HDD + (col & 63)) * SS + s0;
                short4v o;
                o.x = f2bf(acc[fm][fn][0] + bv_); o.y = f2bf(acc[fm][fn][1] + bv_);
                o.z = f2bf(acc[fm][fn][2] + bv_); o.w = f2bf(acc[fm][fn][3] + bv_);
                *(short4v*)&vt[addr] = o;
            }
        }
    }
}

// ---------------------------------------------------------------------------
// Output GEMM — plain swizzled GEMM. 64x64 tile, BK=64, f32 out + bias.
// ---------------------------------------------------------------------------
#define OM 64
#define ON 64
#define OK 64

__global__ __launch_bounds__(256) void k_gemm_out(
    const short* __restrict__ A, const short* __restrict__ W,
    const float* __restrict__ bias, float* __restrict__ C) {
    __shared__ __align__(16) short As[OM * OK];   // 8 KB
    __shared__ __align__(16) short Bs[ON * OK];   // 8 KB
    const int bm = blockIdx.y * OM;
    const int bn = blockIdx.x * ON;
    const int tid = threadIdx.x;
    const int lane = tid & 63;
    const int wid = tid >> 6;
    const int wm = wid & 1;
    const int wn = wid >> 1;
    const int lr = lane & 15;
    const int kq = lane >> 4;

    f32x4 acc[2][2];
#pragma unroll
    for (int i = 0; i < 2; ++i)
#pragma unroll
        for (int j = 0; j < 2; ++j) acc[i][j] = (f32x4)0.0f;

    for (int k0 = 0; k0 < DD; k0 += OK) {
#pragma unroll
        for (int i = 0; i < 2; ++i) {
            int t2 = i * 256 + tid;
            int r = t2 >> 3;
            int cs = (t2 & 7) ^ (r & 7);
            __builtin_amdgcn_global_load_lds(
                (const __attribute__((address_space(1))) unsigned*)(A + (size_t)(bm + r) * DD + k0 + (cs << 3)),
                (__attribute__((address_space(3))) unsigned*)&As[t2 * 8], 16, 0, 0);
        }
#pragma unroll
        for (int i = 0; i < 2; ++i) {
            int t2 = i * 256 + tid;
            int r = t2 >> 3;
            int cs = (t2 & 7) ^ (r & 7);
            __builtin_amdgcn_global_load_lds(
                (const __attribute__((address_space(1))) unsigned*)(W + (size_t)(bn + r) * DD + k0 + (cs << 3)),
                (__attribute__((address_space(3))) unsigned*)&Bs[t2 * 8], 16, 0, 0);
        }
        __syncthreads();

        bf16x8 af[2][2], bfr[2][2];
#pragma unroll
        for (int f = 0; f < 2; ++f) {
            int rowa = wm * 32 + f * 16 + lr;
            int rowb = wn * 32 + f * 16 + lr;
#pragma unroll
            for (int ks = 0; ks < 2; ++ks) {
                int ca = (((ks << 2) | kq)) ^ (rowa & 7);
                int cb = (((ks << 2) | kq)) ^ (rowb & 7);
                af[f][ks] = *(const bf16x8*)&As[rowa * OK + (ca << 3)];
                bfr[f][ks] = *(const bf16x8*)&Bs[rowb * OK + (cb << 3)];
            }
        }
#pragma unroll
        for (int fm = 0; fm < 2; ++fm)
#pragma unroll
            for (int fn = 0; fn < 2; ++fn)
#pragma unroll
                for (int ks = 0; ks < 2; ++ks)
                    acc[fm][fn] = __builtin_amdgcn_mfma_f32_16x16x32_bf16(
                        af[fm][ks], bfr[fn][ks], acc[fm][fn], 0, 0, 0);
        __syncthreads();
    }

#pragma unroll
    for (int fm = 0; fm < 2; ++fm) {
        int row0 = bm + wm * 32 + fm * 16 + kq * 4;
#pragma unroll
        for (int fn = 0; fn < 2; ++fn) {
            int col = bn + wn * 32 + fn * 16 + lr;
            float bv_ = bias[col];
#pragma unroll
            for (int j = 0; j < 4; ++j)
                C[(size_t)(row0 + j) * DD + col] = acc[fm][fn][j] + bv_;
        }
    }
}

// ---------------------------------------------------------------------------
// MFMA flash attention — R17-exact body; NEW: grid swapped to (bh, qtile) so
// linear block id = bh + 32*q -> XCD = bh%8 independent of q: all 8 q-blocks
// of one head land on ONE XCD; each XCD serves 4 heads = 1 MB KV (L2-fits).
// Converts HBM-latency staging misses into L2 hits (latency-bound regime).
// ---------------------------------------------------------------------------
__global__ __launch_bounds__(512) void k_attn(
    const short* __restrict__ qb, const short* __restrict__ kb,
    const short* __restrict__ vt, const float* __restrict__ mask,
    short* __restrict__ ctx) {
    __shared__ __align__(16) short Kls[2][2][64 * 64];   // [kvh][dbuf] 32 KB
    __shared__ __align__(16) short Vls[2][2][64 * 64];   // 32 KB

    const int bh = blockIdx.x;           // SWAPPED: bh fastest -> XCD = bh%8
    const int b = bh >> 4;
    const int h = bh & 15;
    const int q0 = blockIdx.y << 7;
    const int tid = threadIdx.x;
    const int gtid = tid & 255;          // thread within kv-group
    const int kvh = tid >> 8;            // 0 or 1
    const int lane = tid & 63;
    const int w4 = (tid >> 6) & 3;       // wave within group: q sub-tile
    const int ql = lane & 31;
    const int hi = lane >> 5;
    const int rsw = ql & 7;
    const int tbase = kvh << 9;          // 0 or 512
    const float scale2 = 0.125f * LOG2E;
    const float mval2 = MASK_VAL * LOG2E;

    const short* khead = kb + (size_t)b * SS * DD + h * HDD;
    const short* vhead = vt + (size_t)bh * HDD * SS;
    const float* maskp = mask + b * SS;

    bf16x8 qf0, qf1, qf2, qf3;
    {
        const short* qrow = qb + ((size_t)(b * SS + q0 + w4 * 32 + ql)) * DD + h * HDD + hi * 8;
        qf0 = *(const bf16x8*)(qrow);
        qf1 = *(const bf16x8*)(qrow + 16);
        qf2 = *(const bf16x8*)(qrow + 32);
        qf3 = *(const bf16x8*)(qrow + 48);
    }

    auto stage = [&](int t0, int bi) {
        const short* kbase = khead + (size_t)t0 * DD;
        const short* vbase = vhead + t0;
#pragma unroll
        for (int i = 0; i < 2; ++i) {
            int t = i * 256 + gtid;
            int r = t >> 3;
            int cs = (t & 7) ^ (r & 7);
            __builtin_amdgcn_global_load_lds(
                (const __attribute__((address_space(1))) unsigned*)(kbase + (size_t)r * DD + cs * 8),
                (__attribute__((address_space(3))) unsigned*)&Kls[kvh][bi][t * 8], 16, 0, 0);
        }
#pragma unroll
        for (int i = 0; i < 2; ++i) {
            int t = i * 256 + gtid;
            int r = t >> 3;
            int cs = (t & 7) ^ (r & 7);
            __builtin_amdgcn_global_load_lds(
                (const __attribute__((address_space(1))) unsigned*)(vbase + (size_t)r * SS + cs * 8),
                (__attribute__((address_space(3))) unsigned*)&Vls[kvh][bi][t * 8], 16, 0, 0);
        }
    };

    float m_r = -3.0e38f, l_r = 0.0f;
    f32x16 O0 = (f32x16)0.0f, O1 = (f32x16)0.0f;

    auto body = [&](int t0, int cur, int tail) {
        const short* Kb = &Kls[kvh][cur][0];
        const short* Vb = &Vls[kvh][cur][0];

        f32x16 s0 = (f32x16)0.0f, s1 = (f32x16)0.0f;
        __builtin_amdgcn_s_setprio(1);
#pragma unroll
        for (int step = 0; step < 4; ++step) {
            int cpos = ((step << 1) | hi) ^ rsw;
            bf16x8 k0 = *(const bf16x8*)&Kb[ql * 64 + (cpos << 3)];
            bf16x8 k1 = *(const bf16x8*)&Kb[(32 + ql) * 64 + (cpos << 3)];
            bf16x8 qf = (step == 0) ? qf0 : (step == 1) ? qf1 : (step == 2) ? qf2 : qf3;
            s0 = __builtin_amdgcn_mfma_f32_32x32x16_bf16(k0, qf, s0, 0, 0, 0);
            s1 = __builtin_amdgcn_mfma_f32_32x32x16_bf16(k1, qf, s1, 0, 0, 0);
        }
        __builtin_amdgcn_s_setprio(0);

#pragma unroll
        for (int g = 0; g < 4; ++g) {
            float4 a4 = *(const float4*)&maskp[t0 + 8 * g + 4 * hi];
            float4 b4 = *(const float4*)&maskp[t0 + 32 + 8 * g + 4 * hi];
            s0[4 * g + 0] = fmaf(s0[4 * g + 0], scale2, (1.0f - a4.x) * mval2);
            s0[4 * g + 1] = fmaf(s0[4 * g + 1], scale2, (1.0f - a4.y) * mval2);
            s0[4 * g + 2] = fmaf(s0[4 * g + 2], scale2, (1.0f - a4.z) * mval2);
            s0[4 * g + 3] = fmaf(s0[4 * g + 3], scale2, (1.0f - a4.w) * mval2);
            s1[4 * g + 0] = fmaf(s1[4 * g + 0], scale2, (1.0f - b4.x) * mval2);
            s1[4 * g + 1] = fmaf(s1[4 * g + 1], scale2, (1.0f - b4.y) * mval2);
            s1[4 * g + 2] = fmaf(s1[4 * g + 2], scale2, (1.0f - b4.z) * mval2);
            s1[4 * g + 3] = fmaf(s1[4 * g + 3], scale2, (1.0f - b4.w) * mval2);
        }

        float mt[16];
#pragma unroll
        for (int r = 0; r < 16; ++r) mt[r] = fmaxf(s0[r], s1[r]);
#pragma unroll
        for (int st = 8; st > 0; st >>= 1)
#pragma unroll
            for (int r = 0; r < 8; ++r)
                if (r < st) mt[r] = fmaxf(mt[r], mt[r + st]);
        float mx = fmaxf(mt[0], __shfl_xor(mt[0], 32));

        bool need = mx > m_r + 8.0f;   // exp2 domain: P bounded by 2^8
        if (__any(need)) {
            float mn = fmaxf(m_r, mx);
            float alpha = v_exp2(m_r - mn);
            m_r = mn;
            l_r *= alpha;
#pragma unroll
            for (int r = 0; r < 16; ++r) {
                int qrow = (r & 3) + 8 * (r >> 2) + 4 * hi;
                float al = __shfl(alpha, qrow, 64);
                O0[r] *= al;
                O1[r] *= al;
            }
        }

        float st0[16];
#pragma unroll
        for (int r = 0; r < 16; ++r) {
            s0[r] = v_exp2(s0[r] - m_r);
            s1[r] = v_exp2(s1[r] - m_r);
            st0[r] = s0[r] + s1[r];
        }
#pragma unroll
        for (int st = 8; st > 0; st >>= 1)
#pragma unroll
            for (int r = 0; r < 8; ++r)
                if (r < st) st0[r] += st0[r + st];
        l_r += st0[0] + __shfl_xor(st0[0], 32);

        unsigned w0 = cvt_pk_bf16(s0[0], s0[1]),  w1 = cvt_pk_bf16(s0[2], s0[3]);
        unsigned w2 = cvt_pk_bf16(s0[4], s0[5]),  w3 = cvt_pk_bf16(s0[6], s0[7]);
        unsigned w4_ = cvt_pk_bf16(s0[8], s0[9]),  w5 = cvt_pk_bf16(s0[10], s0[11]);
        unsigned w6 = cvt_pk_bf16(s0[12], s0[13]), w7 = cvt_pk_bf16(s0[14], s0[15]);
        plane32_swap(w0, w2); plane32_swap(w1, w3);
        plane32_swap(w4_, w6); plane32_swap(w5, w7);
        uint4v f0 = {w0, w1, w2, w3};
        uint4v f1 = {w4_, w5, w6, w7};
        unsigned x0 = cvt_pk_bf16(s1[0], s1[1]),  x1 = cvt_pk_bf16(s1[2], s1[3]);
        unsigned x2 = cvt_pk_bf16(s1[4], s1[5]),  x3 = cvt_pk_bf16(s1[6], s1[7]);
        unsigned x4 = cvt_pk_bf16(s1[8], s1[9]),  x5 = cvt_pk_bf16(s1[10], s1[11]);
        unsigned x6 = cvt_pk_bf16(s1[12], s1[13]), x7 = cvt_pk_bf16(s1[14], s1[15]);
        plane32_swap(x0, x2); plane32_swap(x1, x3);
        plane32_swap(x4, x6); plane32_swap(x5, x7);
        uint4v f2 = {x0, x1, x2, x3};
        uint4v f3 = {x4, x5, x6, x7};

        bf16x8 pf0 = __builtin_bit_cast(bf16x8, f0);
        bf16x8 pf1 = __builtin_bit_cast(bf16x8, f1);
        bf16x8 pf2 = __builtin_bit_cast(bf16x8, f2);
        bf16x8 pf3 = __builtin_bit_cast(bf16x8, f3);

        if (tail) { asm volatile("s_waitcnt vmcnt(0)\n\ts_barrier" ::: "memory"); }
        else      { asm volatile("s_waitcnt vmcnt(4)\n\ts_barrier" ::: "memory"); }

        __builtin_amdgcn_s_setprio(1);
#pragma unroll
        for (int ks = 0; ks < 4; ++ks) {
            int cpos = ((ks << 1) | hi) ^ rsw;
            bf16x8 pf = (ks == 0) ? pf0 : (ks == 1) ? pf1 : (ks == 2) ? pf2 : pf3;
            bf16x8 v0 = *(const bf16x8*)&Vb[ql * 64 + (cpos << 3)];
            bf16x8 v1 = *(const bf16x8*)&Vb[(32 + ql) * 64 + (cpos << 3)];
            O0 = __builtin_amdgcn_mfma_f32_32x32x16_bf16(pf, v0, O0, 0, 0, 0);
            O1 = __builtin_amdgcn_mfma_f32_32x32x16_bf16(pf, v1, O1, 0, 0, 0);
        }
        __builtin_amdgcn_s_setprio(0);
    };

    stage(tbase, 0);
    for (int it = 0; it < 7; ++it) {
        stage(tbase + ((it + 1) << 6), (it + 1) & 1);
        asm volatile("s_waitcnt vmcnt(6)\n\ts_barrier" ::: "memory");   // K(it) ready
        body(tbase + (it << 6), it & 1, 0);
        asm volatile("s_barrier" ::: "memory");                         // buf reuse guard
    }
    asm volatile("s_waitcnt vmcnt(2)\n\ts_barrier" ::: "memory");       // K(7) ready
    body(tbase + (7 << 6), 1, 1);

    // ---- in-LDS fp32 merge of the two kv-halves ----
    __syncthreads();                                   // all K/V reads done
    float* osh = (float*)&Kls[0][0][0];                // 4 x 2048 floats (32 KB)
    float* mlsh = (float*)&Vls[0][0][0];               // 4 x 64 floats
    if (kvh == 1) {
        float* obuf = osh + w4 * 2048;
#pragma unroll
        for (int r = 0; r < 16; ++r) {
            int qrow = (r & 3) + 8 * (r >> 2) + 4 * hi;
            obuf[qrow * 64 + ql] = O0[r];
            obuf[qrow * 64 + 32 + ql] = O1[r];
        }
        if (lane < 32) {
            mlsh[w4 * 64 + ql] = m_r;
            mlsh[w4 * 64 + 32 + ql] = l_r;
        }
    }
    __syncthreads();
    if (kvh == 0) {
        float* obuf = osh + w4 * 2048;
        float m2 = mlsh[w4 * 64 + ql];
        float l2 = mlsh[w4 * 64 + 32 + ql];
        float m = fmaxf(m_r, m2);
        float a1 = v_exp2(m_r - m), a2 = v_exp2(m2 - m);
        float inv = 1.0f / (l_r * a1 + l2 * a2);
        float c1 = a1 * inv, c2 = a2 * inv;
        short* cb = ctx + ((size_t)(b * SS + q0 + w4 * 32)) * DD + h * HDD;
#pragma unroll
        for (int r = 0; r < 16; ++r) {
            int qrow = (r & 3) + 8 * (r >> 2) + 4 * hi;
            float cc1 = __shfl(c1, qrow, 64);
            float cc2 = __shfl(c2, qrow, 64);
            float ob0 = obuf[qrow * 64 + ql];
            float ob1 = obuf[qrow * 64 + 32 + ql];
            cb[(size_t)qrow * DD + ql]      = f2bf(O0[r] * cc1 + ob0 * cc2);
            cb[(size_t)qrow * DD + 32 + ql] = f2bf(O1[r] * cc1 + ob1 * cc2);
        }
    }
}

// ---------------------------------------------------------------------------
extern "C" void kernel_launch(void* const* d_in, const int* in_sizes, int n_in,
                              void* d_out, int out_size, void* d_ws, size_t ws_size,
                              hipStream_t stream) {
    const float* h    = (const float*)d_in[0];
    const float* mask = (const float*)d_in[1];
    const float* wq   = (const float*)d_in[2];
    const float* bq   = (const float*)d_in[3];
    const float* wk   = (const float*)d_in[4];
    const float* bk   = (const float*)d_in[5];
    const float* wv   = (const float*)d_in[6];
    const float* bv   = (const float*)d_in[7];
    const float* wo   = (const float*)d_in[8];
    const float* bo   = (const float*)d_in[9];
    float* out = (float*)d_out;

    char* base = (char*)d_ws;
    short* x_bf  = (short*)base;                       // 4 MB @ 0
    short* w_bf  = (short*)(base + (4u << 20));        // 8 MB @ 4
    short* q_bf  = (short*)(base + (12u << 20));       // 4 MB @ 12
    short* k_bf  = (short*)(base + (16u << 20));       // 4 MB @ 16
    short* v_t   = (short*)(base + (20u << 20));       // 4 MB @ 20
    short* ctxbf = (short*)(base + (24u << 20));       // 4 MB @ 24

    k_prep<<<3072, 256, 0, stream>>>(h, wq, wk, wv, wo, x_bf, w_bf);

    dim3 gqkv(DD / QBN, BB * SS / QBM, 3);
    k_gemm_qkv<<<gqkv, 256, 0, stream>>>(x_bf, w_bf, bq, bk, bv, q_bf, k_bf, v_t);

    dim3 gattn(BB * HH, SS / 128);   // SWAPPED: bh fastest -> XCD locality
    k_attn<<<gattn, 512, 0, stream>>>(q_bf, k_bf, v_t, mask, ctxbf);

    dim3 gout(DD / ON, BB * SS / OM);
    k_gemm_out<<<gout, 256, 0, stream>>>(ctxbf, w_bf + (size_t)3 * DD * DD, bo, out);
}

// Round 19
// 63.579 us; speedup vs baseline: 1.1767x; 1.0142x over previous
//
#include <hip/hip_runtime.h>
#include <hip/hip_bf16.h>

#define BB 2
#define SS 1024
#define DD 1024
#define HH 16
#define HDD 64
#define MASK_VAL -10000.0f
#define LOG2E 1.44269504f
#define BSD (BB * SS * DD)   // 2097152

typedef __attribute__((ext_vector_type(8))) short bf16x8;
typedef __attribute__((ext_vector_type(4))) short short4v;
typedef __attribute__((ext_vector_type(4))) float f32x4;
typedef __attribute__((ext_vector_type(16))) float f32x16;
typedef __attribute__((ext_vector_type(4))) unsigned int uint4v;

__device__ __forceinline__ short f2bf(float f) {
    union { float f; unsigned u; } v; v.f = f;
    unsigned r = v.u + 0x7FFFu + ((v.u >> 16) & 1u);   // RN-even
    return (short)(r >> 16);
}
__device__ __forceinline__ float bf2f(short s) {
    union { unsigned u; float f; } v;
    v.u = ((unsigned)(unsigned short)s) << 16;
    return v.f;
}
__device__ __forceinline__ unsigned cvt_pk_bf16(float lo, float hi) {
    unsigned r;
    asm("v_cvt_pk_bf16_f32 %0, %1, %2" : "=v"(r) : "v"(lo), "v"(hi));
    return r;
}
// bare v_exp_f32: computes 2^x (exp2 domain; log2e pre-folded into operands)
__device__ __forceinline__ float v_exp2(float x) {
    float r;
    asm("v_exp_f32 %0, %1" : "=v"(r) : "v"(x));
    return r;
}
__device__ __forceinline__ void plane32_swap(unsigned& a, unsigned& b) {
#if __has_builtin(__builtin_amdgcn_permlane32_swap)
    auto r = __builtin_amdgcn_permlane32_swap(a, b, false, false);
    a = r[0]; b = r[1];
#else
    unsigned as = (unsigned)__shfl_xor((int)a, 32);
    unsigned bs = (unsigned)__shfl_xor((int)b, 32);
    bool lo = ((threadIdx.x & 63) < 32);
    unsigned na = lo ? a : bs;
    unsigned nb = lo ? as : b;
    a = na; b = nb;
#endif
}

// ---------------------------------------------------------------------------
// fused prep, compact grid (3072 blocks)
// ---------------------------------------------------------------------------
__global__ __launch_bounds__(256) void k_prep(
    const float* __restrict__ h,
    const float* __restrict__ wq, const float* __restrict__ wk,
    const float* __restrict__ wv, const float* __restrict__ wo,
    short* __restrict__ xbf, short* __restrict__ wbf) {
    int id = blockIdx.x;
    if (id < 1024) {
        int i = id * 256 + threadIdx.x;
        const float4* h0 = (const float4*)h;
        const float4* h1 = (const float4*)(h + (size_t)BSD);
        float4 a0 = h0[2 * i], a1 = h0[2 * i + 1];
        float4 b0 = h1[2 * i], b1 = h1[2 * i + 1];
        bf16x8 o;
        o[0] = f2bf(a0.x + b0.x); o[1] = f2bf(a0.y + b0.y);
        o[2] = f2bf(a0.z + b0.z); o[3] = f2bf(a0.w + b0.w);
        o[4] = f2bf(a1.x + b1.x); o[5] = f2bf(a1.y + b1.y);
        o[6] = f2bf(a1.z + b1.z); o[7] = f2bf(a1.w + b1.w);
        ((bf16x8*)xbf)[i] = o;
    } else {
        int zi = (id - 1024) >> 9;
        int i = ((id - 1024) & 511) * 256 + threadIdx.x;
        const float* src = (zi == 0) ? wq : (zi == 1) ? wk : (zi == 2) ? wv : wo;
        short* dst = wbf + (size_t)zi * (DD * DD);
        const float4* s4 = (const float4*)src;
        float4 a0 = s4[2 * i], a1 = s4[2 * i + 1];
        bf16x8 o;
        o[0] = f2bf(a0.x); o[1] = f2bf(a0.y); o[2] = f2bf(a0.z); o[3] = f2bf(a0.w);
        o[4] = f2bf(a1.x); o[5] = f2bf(a1.y); o[6] = f2bf(a1.z); o[7] = f2bf(a1.w);
        ((bf16x8*)dst)[i] = o;
    }
}

// ---------------------------------------------------------------------------
// QKV bf16 MFMA GEMM — R14-exact: 128x64 tile, BK=64, XOR chunk-swizzled LDS.
// ---------------------------------------------------------------------------
#define QBM 128
#define QBN 64
#define QBK 64

__global__ __launch_bounds__(256) void k_gemm_qkv(
    const short* __restrict__ xbf, const short* __restrict__ wbf,
    const float* __restrict__ bq, const float* __restrict__ bk,
    const float* __restrict__ bv,
    short* __restrict__ qb, short* __restrict__ kb, short* __restrict__ vt) {
    __shared__ __align__(16) short As[QBM * QBK];   // 16 KB
    __shared__ __align__(16) short Bs[QBN * QBK];   // 8 KB
    const int z = blockIdx.z;
    const short* W = wbf + (size_t)z * (DD * DD);
    const float* bias = (z == 0) ? bq : (z == 1) ? bk : bv;
    const int bm = blockIdx.y * QBM;
    const int bn = blockIdx.x * QBN;
    const int tid = threadIdx.x;
    const int lane = tid & 63;
    const int wid = tid >> 6;
    const int wm = wid >> 1;
    const int wn = wid & 1;
    const int lr = lane & 15;
    const int kq = lane >> 4;

    f32x4 acc[4][2];
#pragma unroll
    for (int i = 0; i < 4; ++i)
#pragma unroll
        for (int j = 0; j < 2; ++j) acc[i][j] = (f32x4)0.0f;

    for (int k0 = 0; k0 < DD; k0 += QBK) {
#pragma unroll
        for (int i = 0; i < 4; ++i) {
            int s = i * 256 + tid;
            int r = s >> 3;
            int cs = (s & 7) ^ (r & 7);
            __builtin_amdgcn_global_load_lds(
                (const __attribute__((address_space(1))) unsigned*)(xbf + (size_t)(bm + r) * DD + k0 + (cs << 3)),
                (__attribute__((address_space(3))) unsigned*)&As[s * 8], 16, 0, 0);
        }
#pragma unroll
        for (int i = 0; i < 2; ++i) {
            int s = i * 256 + tid;
            int r = s >> 3;
            int cs = (s & 7) ^ (r & 7);
            __builtin_amdgcn_global_load_lds(
                (const __attribute__((address_space(1))) unsigned*)(W + (size_t)(bn + r) * DD + k0 + (cs << 3)),
                (__attribute__((address_space(3))) unsigned*)&Bs[s * 8], 16, 0, 0);
        }
        __syncthreads();

        bf16x8 af[4][2], bfr[2][2];
#pragma unroll
        for (int f = 0; f < 4; ++f) {
            int row = wm * 64 + f * 16 + lr;
#pragma unroll
            for (int ks = 0; ks < 2; ++ks) {
                int cpos = ((ks << 2) | kq) ^ (row & 7);
                af[f][ks] = *(const bf16x8*)&As[row * QBK + (cpos << 3)];
            }
        }
#pragma unroll
        for (int g = 0; g < 2; ++g) {
            int row = wn * 32 + g * 16 + lr;
#pragma unroll
            for (int ks = 0; ks < 2; ++ks) {
                int cpos = ((ks << 2) | kq) ^ (row & 7);
                bfr[g][ks] = *(const bf16x8*)&Bs[row * QBK + (cpos << 3)];
            }
        }
#pragma unroll
        for (int fm = 0; fm < 4; ++fm)
#pragma unroll
            for (int fn = 0; fn < 2; ++fn)
#pragma unroll
                for (int ks = 0; ks < 2; ++ks)
                    acc[fm][fn] = __builtin_amdgcn_mfma_f32_16x16x32_bf16(
                        af[fm][ks], bfr[fn][ks], acc[fm][fn], 0, 0, 0);
        __syncthreads();
    }

    if (z < 2) {
        short* C = (z == 0) ? qb : kb;
#pragma unroll
        for (int fm = 0; fm < 4; ++fm) {
            int row0 = bm + wm * 64 + fm * 16 + kq * 4;
#pragma unroll
            for (int fn = 0; fn < 2; ++fn) {
                int col = bn + wn * 32 + fn * 16 + lr;
                float bv_ = bias[col];
#pragma unroll
                for (int j = 0; j < 4; ++j)
                    C[(size_t)(row0 + j) * DD + col] = f2bf(acc[fm][fn][j] + bv_);
            }
        }
    } else {
#pragma unroll
        for (int fm = 0; fm < 4; ++fm) {
            int row0 = bm + wm * 64 + fm * 16 + kq * 4;
            int bidx = row0 >> 10, s0 = row0 & 1023;
#pragma unroll
            for (int fn = 0; fn < 2; ++fn) {
                int col = bn + wn * 32 + fn * 16 + lr;
                float bv_ = bias[col];
                size_t addr = ((size_t)(bidx * HH + (col >> 6)) * HDD + (col & 63)) * SS + s0;
                short4v o;
                o.x = f2bf(acc[fm][fn][0] + bv_); o.y = f2bf(acc[fm][fn][1] + bv_);
                o.z = f2bf(acc[fm][fn][2] + bv_); o.w = f2bf(acc[fm][fn][3] + bv_);
                *(short4v*)&vt[addr] = o;
            }
        }
    }
}

// ---------------------------------------------------------------------------
// Output GEMM — plain swizzled GEMM. 64x64 tile, BK=64, f32 out + bias.
// ---------------------------------------------------------------------------
#define OM 64
#define ON 64
#define OK 64

__global__ __launch_bounds__(256) void k_gemm_out(
    const short* __restrict__ A, const short* __restrict__ W,
    const float* __restrict__ bias, float* __restrict__ C) {
    __shared__ __align__(16) short As[OM * OK];   // 8 KB
    __shared__ __align__(16) short Bs[ON * OK];   // 8 KB
    const int bm = blockIdx.y * OM;
    const int bn = blockIdx.x * ON;
    const int tid = threadIdx.x;
    const int lane = tid & 63;
    const int wid = tid >> 6;
    const int wm = wid & 1;
    const int wn = wid >> 1;
    const int lr = lane & 15;
    const int kq = lane >> 4;

    f32x4 acc[2][2];
#pragma unroll
    for (int i = 0; i < 2; ++i)
#pragma unroll
        for (int j = 0; j < 2; ++j) acc[i][j] = (f32x4)0.0f;

    for (int k0 = 0; k0 < DD; k0 += OK) {
#pragma unroll
        for (int i = 0; i < 2; ++i) {
            int t2 = i * 256 + tid;
            int r = t2 >> 3;
            int cs = (t2 & 7) ^ (r & 7);
            __builtin_amdgcn_global_load_lds(
                (const __attribute__((address_space(1))) unsigned*)(A + (size_t)(bm + r) * DD + k0 + (cs << 3)),
                (__attribute__((address_space(3))) unsigned*)&As[t2 * 8], 16, 0, 0);
        }
#pragma unroll
        for (int i = 0; i < 2; ++i) {
            int t2 = i * 256 + tid;
            int r = t2 >> 3;
            int cs = (t2 & 7) ^ (r & 7);
            __builtin_amdgcn_global_load_lds(
                (const __attribute__((address_space(1))) unsigned*)(W + (size_t)(bn + r) * DD + k0 + (cs << 3)),
                (__attribute__((address_space(3))) unsigned*)&Bs[t2 * 8], 16, 0, 0);
        }
        __syncthreads();

        bf16x8 af[2][2], bfr[2][2];
#pragma unroll
        for (int f = 0; f < 2; ++f) {
            int rowa = wm * 32 + f * 16 + lr;
            int rowb = wn * 32 + f * 16 + lr;
#pragma unroll
            for (int ks = 0; ks < 2; ++ks) {
                int ca = (((ks << 2) | kq)) ^ (rowa & 7);
                int cb = (((ks << 2) | kq)) ^ (rowb & 7);
                af[f][ks] = *(const bf16x8*)&As[rowa * OK + (ca << 3)];
                bfr[f][ks] = *(const bf16x8*)&Bs[rowb * OK + (cb << 3)];
            }
        }
#pragma unroll
        for (int fm = 0; fm < 2; ++fm)
#pragma unroll
            for (int fn = 0; fn < 2; ++fn)
#pragma unroll
                for (int ks = 0; ks < 2; ++ks)
                    acc[fm][fn] = __builtin_amdgcn_mfma_f32_16x16x32_bf16(
                        af[fm][ks], bfr[fn][ks], acc[fm][fn], 0, 0, 0);
        __syncthreads();
    }

#pragma unroll
    for (int fm = 0; fm < 2; ++fm) {
        int row0 = bm + wm * 32 + fm * 16 + kq * 4;
#pragma unroll
        for (int fn = 0; fn < 2; ++fn) {
            int col = bn + wn * 32 + fn * 16 + lr;
            float bv_ = bias[col];
#pragma unroll
            for (int j = 0; j < 4; ++j)
                C[(size_t)(row0 + j) * DD + col] = acc[fm][fn][j] + bv_;
        }
    }
}

// ---------------------------------------------------------------------------
// MFMA flash attention — R18 body; NEW: 256-thread blocks (2 kvh x 2 q-waves,
// 64 q-rows), grid (32 bh, 16 q) = 512 blocks = 2 INDEPENDENT blocks/CU
// (LDS 64 KB each -> exactly 2 fit). Same waves/CU, but two barrier domains:
// when one block stalls at vmcnt+barrier, the other's waves issue.
// vmcnt ladder recomputed for 8-load stages (12/8 main, 4/0 tail).
// ---------------------------------------------------------------------------
__global__ __launch_bounds__(256) void k_attn(
    const short* __restrict__ qb, const short* __restrict__ kb,
    const short* __restrict__ vt, const float* __restrict__ mask,
    short* __restrict__ ctx) {
    __shared__ __align__(16) short Kls[2][2][64 * 64];   // [kvh][dbuf] 32 KB
    __shared__ __align__(16) short Vls[2][2][64 * 64];   // 32 KB

    const int bh = blockIdx.x;           // bh fastest -> XCD = bh%8 (R18 win)
    const int b = bh >> 4;
    const int h = bh & 15;
    const int q0 = blockIdx.y << 6;      // 64 q-rows per block
    const int tid = threadIdx.x;
    const int gtid = tid & 127;          // thread within kv-group (128 thr)
    const int kvh = tid >> 7;            // 0 or 1
    const int lane = tid & 63;
    const int w4 = (tid >> 6) & 1;       // q sub-tile within group (0..1)
    const int ql = lane & 31;
    const int hi = lane >> 5;
    const int rsw = ql & 7;
    const int tbase = kvh << 9;          // 0 or 512
    const float scale2 = 0.125f * LOG2E;
    const float mval2 = MASK_VAL * LOG2E;

    const short* khead = kb + (size_t)b * SS * DD + h * HDD;
    const short* vhead = vt + (size_t)bh * HDD * SS;
    const float* maskp = mask + b * SS;

    bf16x8 qf0, qf1, qf2, qf3;
    {
        const short* qrow = qb + ((size_t)(b * SS + q0 + w4 * 32 + ql)) * DD + h * HDD + hi * 8;
        qf0 = *(const bf16x8*)(qrow);
        qf1 = *(const bf16x8*)(qrow + 16);
        qf2 = *(const bf16x8*)(qrow + 32);
        qf3 = *(const bf16x8*)(qrow + 48);
    }

    // stage one 64-KV tile: 8 gload_lds/thread (4 K + 4 V), 128 threads/group
    auto stage = [&](int t0, int bi) {
        const short* kbase = khead + (size_t)t0 * DD;
        const short* vbase = vhead + t0;
#pragma unroll
        for (int i = 0; i < 4; ++i) {
            int t = i * 128 + gtid;       // 0..511 chunks
            int r = t >> 3;
            int cs = (t & 7) ^ (r & 7);
            __builtin_amdgcn_global_load_lds(
                (const __attribute__((address_space(1))) unsigned*)(kbase + (size_t)r * DD + cs * 8),
                (__attribute__((address_space(3))) unsigned*)&Kls[kvh][bi][t * 8], 16, 0, 0);
        }
#pragma unroll
        for (int i = 0; i < 4; ++i) {
            int t = i * 128 + gtid;
            int r = t >> 3;
            int cs = (t & 7) ^ (r & 7);
            __builtin_amdgcn_global_load_lds(
                (const __attribute__((address_space(1))) unsigned*)(vbase + (size_t)r * SS + cs * 8),
                (__attribute__((address_space(3))) unsigned*)&Vls[kvh][bi][t * 8], 16, 0, 0);
        }
    };

    float m_r = -3.0e38f, l_r = 0.0f;
    f32x16 O0 = (f32x16)0.0f, O1 = (f32x16)0.0f;

    auto body = [&](int t0, int cur, int tail) {
        const short* Kb = &Kls[kvh][cur][0];
        const short* Vb = &Vls[kvh][cur][0];

        f32x16 s0 = (f32x16)0.0f, s1 = (f32x16)0.0f;
        __builtin_amdgcn_s_setprio(1);
#pragma unroll
        for (int step = 0; step < 4; ++step) {
            int cpos = ((step << 1) | hi) ^ rsw;
            bf16x8 k0 = *(const bf16x8*)&Kb[ql * 64 + (cpos << 3)];
            bf16x8 k1 = *(const bf16x8*)&Kb[(32 + ql) * 64 + (cpos << 3)];
            bf16x8 qf = (step == 0) ? qf0 : (step == 1) ? qf1 : (step == 2) ? qf2 : qf3;
            s0 = __builtin_amdgcn_mfma_f32_32x32x16_bf16(k0, qf, s0, 0, 0, 0);
            s1 = __builtin_amdgcn_mfma_f32_32x32x16_bf16(k1, qf, s1, 0, 0, 0);
        }
        __builtin_amdgcn_s_setprio(0);

#pragma unroll
        for (int g = 0; g < 4; ++g) {
            float4 a4 = *(const float4*)&maskp[t0 + 8 * g + 4 * hi];
            float4 b4 = *(const float4*)&maskp[t0 + 32 + 8 * g + 4 * hi];
            s0[4 * g + 0] = fmaf(s0[4 * g + 0], scale2, (1.0f - a4.x) * mval2);
            s0[4 * g + 1] = fmaf(s0[4 * g + 1], scale2, (1.0f - a4.y) * mval2);
            s0[4 * g + 2] = fmaf(s0[4 * g + 2], scale2, (1.0f - a4.z) * mval2);
            s0[4 * g + 3] = fmaf(s0[4 * g + 3], scale2, (1.0f - a4.w) * mval2);
            s1[4 * g + 0] = fmaf(s1[4 * g + 0], scale2, (1.0f - b4.x) * mval2);
            s1[4 * g + 1] = fmaf(s1[4 * g + 1], scale2, (1.0f - b4.y) * mval2);
            s1[4 * g + 2] = fmaf(s1[4 * g + 2], scale2, (1.0f - b4.z) * mval2);
            s1[4 * g + 3] = fmaf(s1[4 * g + 3], scale2, (1.0f - b4.w) * mval2);
        }

        float mt[16];
#pragma unroll
        for (int r = 0; r < 16; ++r) mt[r] = fmaxf(s0[r], s1[r]);
#pragma unroll
        for (int st = 8; st > 0; st >>= 1)
#pragma unroll
            for (int r = 0; r < 8; ++r)
                if (r < st) mt[r] = fmaxf(mt[r], mt[r + st]);
        float mx = fmaxf(mt[0], __shfl_xor(mt[0], 32));

        bool need = mx > m_r + 8.0f;   // exp2 domain: P bounded by 2^8
        if (__any(need)) {
            float mn = fmaxf(m_r, mx);
            float alpha = v_exp2(m_r - mn);
            m_r = mn;
            l_r *= alpha;
#pragma unroll
            for (int r = 0; r < 16; ++r) {
                int qrow = (r & 3) + 8 * (r >> 2) + 4 * hi;
                float al = __shfl(alpha, qrow, 64);
                O0[r] *= al;
                O1[r] *= al;
            }
        }

        float st0[16];
#pragma unroll
        for (int r = 0; r < 16; ++r) {
            s0[r] = v_exp2(s0[r] - m_r);
            s1[r] = v_exp2(s1[r] - m_r);
            st0[r] = s0[r] + s1[r];
        }
#pragma unroll
        for (int st = 8; st > 0; st >>= 1)
#pragma unroll
            for (int r = 0; r < 8; ++r)
                if (r < st) st0[r] += st0[r + st];
        l_r += st0[0] + __shfl_xor(st0[0], 32);

        unsigned w0 = cvt_pk_bf16(s0[0], s0[1]),  w1 = cvt_pk_bf16(s0[2], s0[3]);
        unsigned w2 = cvt_pk_bf16(s0[4], s0[5]),  w3 = cvt_pk_bf16(s0[6], s0[7]);
        unsigned w4_ = cvt_pk_bf16(s0[8], s0[9]),  w5 = cvt_pk_bf16(s0[10], s0[11]);
        unsigned w6 = cvt_pk_bf16(s0[12], s0[13]), w7 = cvt_pk_bf16(s0[14], s0[15]);
        plane32_swap(w0, w2); plane32_swap(w1, w3);
        plane32_swap(w4_, w6); plane32_swap(w5, w7);
        uint4v f0 = {w0, w1, w2, w3};
        uint4v f1 = {w4_, w5, w6, w7};
        unsigned x0 = cvt_pk_bf16(s1[0], s1[1]),  x1 = cvt_pk_bf16(s1[2], s1[3]);
        unsigned x2 = cvt_pk_bf16(s1[4], s1[5]),  x3 = cvt_pk_bf16(s1[6], s1[7]);
        unsigned x4 = cvt_pk_bf16(s1[8], s1[9]),  x5 = cvt_pk_bf16(s1[10], s1[11]);
        unsigned x6 = cvt_pk_bf16(s1[12], s1[13]), x7 = cvt_pk_bf16(s1[14], s1[15]);
        plane32_swap(x0, x2); plane32_swap(x1, x3);
        plane32_swap(x4, x6); plane32_swap(x5, x7);
        uint4v f2 = {x0, x1, x2, x3};
        uint4v f3 = {x4, x5, x6, x7};

        bf16x8 pf0 = __builtin_bit_cast(bf16x8, f0);
        bf16x8 pf1 = __builtin_bit_cast(bf16x8, f1);
        bf16x8 pf2 = __builtin_bit_cast(bf16x8, f2);
        bf16x8 pf3 = __builtin_bit_cast(bf16x8, f3);

        // V(it) ready gate: all group loads drained (own vmcnt + block barrier)
        if (tail) { asm volatile("s_waitcnt vmcnt(0)\n\ts_barrier" ::: "memory"); }
        else      { asm volatile("s_waitcnt vmcnt(8)\n\ts_barrier" ::: "memory"); }

        __builtin_amdgcn_s_setprio(1);
#pragma unroll
        for (int ks = 0; ks < 4; ++ks) {
            int cpos = ((ks << 1) | hi) ^ rsw;
            bf16x8 pf = (ks == 0) ? pf0 : (ks == 1) ? pf1 : (ks == 2) ? pf2 : pf3;
            bf16x8 v0 = *(const bf16x8*)&Vb[ql * 64 + (cpos << 3)];
            bf16x8 v1 = *(const bf16x8*)&Vb[(32 + ql) * 64 + (cpos << 3)];
            O0 = __builtin_amdgcn_mfma_f32_32x32x16_bf16(pf, v0, O0, 0, 0, 0);
            O1 = __builtin_amdgcn_mfma_f32_32x32x16_bf16(pf, v1, O1, 0, 0, 0);
        }
        __builtin_amdgcn_s_setprio(0);
    };

    stage(tbase, 0);
    for (int it = 0; it < 7; ++it) {
        stage(tbase + ((it + 1) << 6), (it + 1) & 1);
        asm volatile("s_waitcnt vmcnt(12)\n\ts_barrier" ::: "memory");  // K(it) ready
        body(tbase + (it << 6), it & 1, 0);
        asm volatile("s_barrier" ::: "memory");                         // buf reuse guard
    }
    asm volatile("s_waitcnt vmcnt(4)\n\ts_barrier" ::: "memory");       // K(7) ready
    body(tbase + (7 << 6), 1, 1);

    // ---- in-LDS fp32 merge of the two kv-halves ----
    __syncthreads();                                   // all K/V reads done
    float* osh = (float*)&Kls[0][0][0];                // 2 x 2048 floats (16 KB)
    float* mlsh = (float*)&Vls[0][0][0];               // 2 x 64 floats
    if (kvh == 1) {
        float* obuf = osh + w4 * 2048;
#pragma unroll
        for (int r = 0; r < 16; ++r) {
            int qrow = (r & 3) + 8 * (r >> 2) + 4 * hi;
            obuf[qrow * 64 + ql] = O0[r];
            obuf[qrow * 64 + 32 + ql] = O1[r];
        }
        if (lane < 32) {
            mlsh[w4 * 64 + ql] = m_r;
            mlsh[w4 * 64 + 32 + ql] = l_r;
        }
    }
    __syncthreads();
    if (kvh == 0) {
        float* obuf = osh + w4 * 2048;
        float m2 = mlsh[w4 * 64 + ql];
        float l2 = mlsh[w4 * 64 + 32 + ql];
        float m = fmaxf(m_r, m2);
        float a1 = v_exp2(m_r - m), a2 = v_exp2(m2 - m);
        float inv = 1.0f / (l_r * a1 + l2 * a2);
        float c1 = a1 * inv, c2 = a2 * inv;
        short* cb = ctx + ((size_t)(b * SS + q0 + w4 * 32)) * DD + h * HDD;
#pragma unroll
        for (int r = 0; r < 16; ++r) {
            int qrow = (r & 3) + 8 * (r >> 2) + 4 * hi;
            float cc1 = __shfl(c1, qrow, 64);
            float cc2 = __shfl(c2, qrow, 64);
            float ob0 = obuf[qrow * 64 + ql];
            float ob1 = obuf[qrow * 64 + 32 + ql];
            cb[(size_t)qrow * DD + ql]      = f2bf(O0[r] * cc1 + ob0 * cc2);
            cb[(size_t)qrow * DD + 32 + ql] = f2bf(O1[r] * cc1 + ob1 * cc2);
        }
    }
}

// ---------------------------------------------------------------------------
extern "C" void kernel_launch(void* const* d_in, const int* in_sizes, int n_in,
                              void* d_out, int out_size, void* d_ws, size_t ws_size,
                              hipStream_t stream) {
    const float* h    = (const float*)d_in[0];
    const float* mask = (const float*)d_in[1];
    const float* wq   = (const float*)d_in[2];
    const float* bq   = (const float*)d_in[3];
    const float* wk   = (const float*)d_in[4];
    const float* bk   = (const float*)d_in[5];
    const float* wv   = (const float*)d_in[6];
    const float* bv   = (const float*)d_in[7];
    const float* wo   = (const float*)d_in[8];
    const float* bo   = (const float*)d_in[9];
    float* out = (float*)d_out;

    char* base = (char*)d_ws;
    short* x_bf  = (short*)base;                       // 4 MB @ 0
    short* w_bf  = (short*)(base + (4u << 20));        // 8 MB @ 4
    short* q_bf  = (short*)(base + (12u << 20));       // 4 MB @ 12
    short* k_bf  = (short*)(base + (16u << 20));       // 4 MB @ 16
    short* v_t   = (short*)(base + (20u << 20));       // 4 MB @ 20
    short* ctxbf = (short*)(base + (24u << 20));       // 4 MB @ 24

    k_prep<<<3072, 256, 0, stream>>>(h, wq, wk, wv, wo, x_bf, w_bf);

    dim3 gqkv(DD / QBN, BB * SS / QBM, 3);
    k_gemm_qkv<<<gqkv, 256, 0, stream>>>(x_bf, w_bf, bq, bk, bv, q_bf, k_bf, v_t);

    dim3 gattn(BB * HH, SS / 64);    // bh fastest -> XCD locality; 512 blocks
    k_attn<<<gattn, 256, 0, stream>>>(q_bf, k_bf, v_t, mask, ctxbf);

    dim3 gout(DD / ON, BB * SS / OM);
    k_gemm_out<<<gout, 256, 0, stream>>>(ctxbf, w_bf + (size_t)3 * DD * DD, bo, out);
}